// Round 2
// baseline (1272.657 us; speedup 1.0000x reference)
//
#include <hip/hip_runtime.h>

// ---------------------------------------------------------------------------
// SGFormer forward, MI355X/gfx950.  I/O f32; internal h/q/k/v bf16.
// attn = (q @ (k^T v) * s + N*v) / (q . (sum_k) * s + N),  s = 1/(||q|| ||k||)
// KVt[272][256]: rows 0..255 = (KV*s)^T, row 256 = ksum*s, 257..271 = 0.
//
// R5 lesson: qkv/attn/in all latency-starved (qkv: 1.38 TB/s, MfmaUtil 10.7%,
// occ 27.6%).  R6 (this round):
//  - k,v stored in MFMA C-FRAGMENT layout (8B bf16x4 per lane): qkv stores
//    them with zero barriers / perfect coalescing; attn reads v back with the
//    identical mapping (16x 8B loads, no LDS pass); kv_kernel decodes frags
//    into its LDS transpose.  Only q keeps the row-major bounce (attn stages
//    it as the MFMA A operand).
//  - qkv: B double-buffer prefetch across ki; shfl+atomic reductions (no scr
//    barriers); LDS As 32K + Cb 16x256 (8K) = 40960 B exactly -> 4 blocks/CU.
//  - attn: Cb/rowm/rowr aliased into As (dead after pass 2) -> 35 KB ->
//    4 blocks/CU; h staging issued before fold-1 (latency hidden under it).
//  - in_kernel: B prefetch added to the double-buffered slab loop.
// ---------------------------------------------------------------------------

typedef __attribute__((ext_vector_type(8))) short short8;
typedef __attribute__((ext_vector_type(4))) short short4v;
typedef __attribute__((ext_vector_type(4))) float floatx4;

__device__ __forceinline__ float bf2f(short u) {
    union { unsigned int i; float f; } v;
    v.i = ((unsigned int)(unsigned short)u) << 16;
    return v.f;
}
__device__ __forceinline__ short f2bf(float f) {
    union { float f; unsigned int i; } v; v.f = f;
    unsigned int b = v.i + 0x7fffu + ((v.i >> 16) & 1u);  // RNE
    return (short)(b >> 16);
}

#define HID 256
#define MROWS 100000
#define GBLK 1563            // ceil(MROWS/64)
#define EPSLN 1e-5f

// C-fragment layout: unit = 4 shorts (8B) = rows {m*16+quad*4+0..3}, col
// nb + n*16 + l15, for (blk, wave, m, n, lane).  One store inst = 512B.
__device__ __forceinline__ size_t fragoff(int blk, int w, int m, int n, int lane) {
    return (((((size_t)blk * 4 + w) * 4 + m) * 4 + n) * 64 + lane);
}

// ---- stage a 64x256 bf16 A-tile into LDS via global_load_lds, XOR-swizzled.
__device__ __forceinline__ void stage_a256(const short* __restrict__ A, short* As,
                                           int row0, int wave, int lane)
{
    const int base = wave * 512;
#pragma unroll
    for (int it = 0; it < 8; ++it) {
        int J = base + it * 64 + lane;
        int row = J >> 5, jj = J & 31;
        int c = jj ^ (row & 31);
        int rowg = min(row0 + row, MROWS - 1);
        const short* gp = A + (size_t)rowg * HID + c * 8;
        __builtin_amdgcn_global_load_lds(
            (const __attribute__((address_space(1))) void*)gp,
            (__attribute__((address_space(3))) void*)&As[(size_t)(base + it * 64) * 8],
            16, 0, 0);
    }
}
// ---- same, linear (no swizzle): for tiles read scalar later.
__device__ __forceinline__ void stage_lin256(const short* __restrict__ A, short* As,
                                             int row0, int wave, int lane)
{
    const int base = wave * 512;
#pragma unroll
    for (int it = 0; it < 8; ++it) {
        int J = base + it * 64 + lane;
        int row = J >> 5, jj = J & 31;
        int rowg = min(row0 + row, MROWS - 1);
        const short* gp = A + (size_t)rowg * HID + jj * 8;
        __builtin_amdgcn_global_load_lds(
            (const __attribute__((address_space(1))) void*)gp,
            (__attribute__((address_space(3))) void*)&As[(size_t)(base + it * 64) * 8],
            16, 0, 0);
    }
}
__device__ __forceinline__ short8 read_a256(const short* As, int m, int ki, int quad, int l15)
{
    int row = m * 16 + l15;
    int phys = (ki * 4 + quad) ^ (row & 31);
    return *(const short8*)&As[((size_t)row * 32 + phys) * 8];
}

// ---------------------------------------------------------------------------
// Fused q/k/v projection.  k,v -> fragment layout (no barriers); q -> bounced
// row-major.  Frobenius sumsq for q,k and column-sum for k via shfl+atomics.
// ---------------------------------------------------------------------------
__global__ __launch_bounds__(256, 4)
void qkv_kernel(const short* __restrict__ h,
                const short* __restrict__ BTq, const short* __restrict__ BTk,
                const short* __restrict__ BTv,
                const float* __restrict__ bq, const float* __restrict__ bk,
                const float* __restrict__ bv,
                short* __restrict__ qO, short* __restrict__ kF, short* __restrict__ vF,
                float* __restrict__ sqq, float* __restrict__ sqk,
                float* __restrict__ ksum)
{
    __shared__ short As[64 * 256];      // 32 KB
    __shared__ short Cb[16 * 256];      // 8 KB  (total 40960 -> 4 blocks/CU)

    const int tid = threadIdx.x, wave = tid >> 6, lane = tid & 63;
    const int quad = lane >> 4, l15 = lane & 15;
    const int blk = blockIdx.x;
    const int row0 = blk * 64, nb = wave * 64;

    stage_a256(h, As, row0, wave, lane);
    __syncthreads();

    floatx4 acc[4][4];

    auto bload = [&](const short* __restrict__ BT, int n, int ki) -> short8 {
        return *(const short8*)(BT + (size_t)(nb + n * 16 + l15) * 256 + ki * 32 + quad * 8);
    };
    auto gemm256 = [&](const short* __restrict__ BT) {
#pragma unroll
        for (int m = 0; m < 4; m++)
#pragma unroll
            for (int n = 0; n < 4; n++) acc[m][n] = (floatx4)0.0f;
        short8 bc[4];
#pragma unroll
        for (int n = 0; n < 4; ++n) bc[n] = bload(BT, n, 0);
#pragma unroll
        for (int ki = 0; ki < 8; ++ki) {
            short8 bnx[4];
            if (ki < 7)
#pragma unroll
                for (int n = 0; n < 4; ++n) bnx[n] = bload(BT, n, ki + 1);
            short8 a[4];
#pragma unroll
            for (int m = 0; m < 4; ++m) a[m] = read_a256(As, m, ki, quad, l15);
#pragma unroll
            for (int n = 0; n < 4; ++n)
#pragma unroll
                for (int m = 0; m < 4; ++m)
                    acc[m][n] = __builtin_amdgcn_mfma_f32_16x16x32_bf16(a[m], bc[n], acc[m][n], 0, 0, 0);
            if (ki < 7)
#pragma unroll
                for (int n = 0; n < 4; ++n) bc[n] = bnx[n];
        }
    };

    float bn[4];

    // ---------------- K ----------------
    gemm256(BTk);
#pragma unroll
    for (int n = 0; n < 4; n++) bn[n] = bk[nb + n * 16 + l15];
    {
        float ssq = 0.f;
        float csum[4] = {0.f, 0.f, 0.f, 0.f};
#pragma unroll
        for (int m = 0; m < 4; m++)
#pragma unroll
            for (int r = 0; r < 4; r++) {
                int rl = m * 16 + quad * 4 + r;
                bool valid = (row0 + rl) < MROWS;
#pragma unroll
                for (int n = 0; n < 4; n++) {
                    float val = acc[m][n][r] + bn[n];
                    acc[m][n][r] = val;
                    if (valid) { ssq += val * val; csum[n] += val; }
                }
            }
#pragma unroll
        for (int off = 32; off; off >>= 1) ssq += __shfl_down(ssq, off);
        if (lane == 0) atomicAdd(sqk, ssq);
#pragma unroll
        for (int n = 0; n < 4; n++) {
            float cv = csum[n];
            cv += __shfl_xor(cv, 16);
            cv += __shfl_xor(cv, 32);
            if (quad == 0) atomicAdd(&ksum[nb + n * 16 + l15], cv);
        }
#pragma unroll
        for (int m = 0; m < 4; ++m)
#pragma unroll
            for (int n = 0; n < 4; ++n) {
                short4v s4;
#pragma unroll
                for (int r = 0; r < 4; ++r) s4[r] = f2bf(acc[m][n][r]);
                *(short4v*)(kF + fragoff(blk, wave, m, n, lane) * 4) = s4;
            }
    }

    // ---------------- V ----------------
    gemm256(BTv);
#pragma unroll
    for (int n = 0; n < 4; n++) bn[n] = bv[nb + n * 16 + l15];
#pragma unroll
    for (int m = 0; m < 4; ++m)
#pragma unroll
        for (int n = 0; n < 4; ++n) {
            short4v s4;
#pragma unroll
            for (int r = 0; r < 4; ++r) s4[r] = f2bf(acc[m][n][r] + bn[n]);
            *(short4v*)(vF + fragoff(blk, wave, m, n, lane) * 4) = s4;
        }

    // ---------------- Q ----------------
    gemm256(BTq);
#pragma unroll
    for (int n = 0; n < 4; n++) bn[n] = bq[nb + n * 16 + l15];
    {
        float ssq = 0.f;
#pragma unroll
        for (int m = 0; m < 4; m++)
#pragma unroll
            for (int r = 0; r < 4; r++) {
                int rl = m * 16 + quad * 4 + r;
                bool valid = (row0 + rl) < MROWS;
#pragma unroll
                for (int n = 0; n < 4; n++) {
                    float val = acc[m][n][r] + bn[n];
                    acc[m][n][r] = val;
                    if (valid) ssq += val * val;
                }
            }
#pragma unroll
        for (int off = 32; off; off >>= 1) ssq += __shfl_down(ssq, off);
        if (lane == 0) atomicAdd(sqq, ssq);
    }
    // bounce q row-major (coalesced 512B lines)
#pragma unroll
    for (int m = 0; m < 4; ++m) {
        __syncthreads();
#pragma unroll
        for (int n = 0; n < 4; ++n)
#pragma unroll
            for (int r = 0; r < 4; ++r)
                Cb[(quad * 4 + r) * 256 + nb + n * 16 + l15] = f2bf(acc[m][n][r]);
        __syncthreads();
#pragma unroll
        for (int ch = tid; ch < 512; ch += 256) {
            int rl = ch >> 5, co = (ch & 31) * 8;
            int row = row0 + m * 16 + rl;
            if (row < MROWS)
                *(short8*)(qO + (size_t)row * 256 + co) = *(const short8*)&Cb[rl * 256 + co];
        }
    }
}

// ---------------------------------------------------------------------------
// Attention epilogue GEMM: acc = q @ KVt_s (den col = KVt row 256, wave 0);
// h = 0.5*(acc + N*v)/den + 0.5*h; LayerNorm; in-place.
// v read directly in fragment layout (16x 8B loads, same mapping as qkv's
// acc).  h staged into As (dead after MFMA) while fold-1 computes.
// Cb / rowm / rowr aliased into As -> 35 KB LDS -> 4 blocks/CU.
// ---------------------------------------------------------------------------
__global__ __launch_bounds__(256, 4)
void attn_kernel(const short* __restrict__ q, const short* __restrict__ KVt,
                 const short* __restrict__ vF, short* __restrict__ h,
                 const float* __restrict__ lng, const float* __restrict__ lnb,
                 float Nf)
{
    __shared__ short As[64 * 256];      // 32 KB
    __shared__ float denA[64];
    __shared__ float redS[64][4], redQ[64][4];
    short* Cb = As;                     // alias: bytes [0, 8192)
    float* rowm = (float*)&As[4352];    // bytes [8704, 8960)
    float* rowr = (float*)&As[4480];    // bytes [8960, 9216)

    const int tid = threadIdx.x, wave = tid >> 6, lane = tid & 63;
    const int quad = lane >> 4, l15 = lane & 15;
    const int blk = blockIdx.x;
    const int row0 = blk * 64, nb = wave * 64;

    stage_a256(q, As, row0, wave, lane);
    __syncthreads();

    floatx4 acc[4][4];
#pragma unroll
    for (int m = 0; m < 4; m++)
#pragma unroll
        for (int n = 0; n < 4; n++) acc[m][n] = (floatx4)0.0f;
    floatx4 accd[4];
#pragma unroll
    for (int m = 0; m < 4; m++) accd[m] = (floatx4)0.0f;

#pragma unroll
    for (int ki = 0; ki < 8; ++ki) {
        short8 a[4];
#pragma unroll
        for (int m = 0; m < 4; ++m) a[m] = read_a256(As, m, ki, quad, l15);
#pragma unroll
        for (int n = 0; n < 4; ++n) {
            short8 b = *(const short8*)(KVt + (size_t)(nb + n * 16 + l15) * 256 + ki * 32 + quad * 8);
#pragma unroll
            for (int m = 0; m < 4; ++m)
                acc[m][n] = __builtin_amdgcn_mfma_f32_16x16x32_bf16(a[m], b, acc[m][n], 0, 0, 0);
        }
        if (wave == 0) {
            short8 bd = *(const short8*)(KVt + (size_t)(256 + l15) * 256 + ki * 32 + quad * 8);
#pragma unroll
            for (int m = 0; m < 4; ++m)
                accd[m] = __builtin_amdgcn_mfma_f32_16x16x32_bf16(a[m], bd, accd[m], 0, 0, 0);
        }
    }
    // v fragment loads (independent; latency hidden under denA + fold-1 setup)
    short4v vr[4][4];
#pragma unroll
    for (int m = 0; m < 4; ++m)
#pragma unroll
        for (int n = 0; n < 4; ++n)
            vr[m][n] = *(const short4v*)(vF + fragoff(blk, wave, m, n, lane) * 4);

    if (wave == 0 && l15 == 0) {
#pragma unroll
        for (int m = 0; m < 4; m++)
#pragma unroll
            for (int r = 0; r < 4; r++)
                denA[m * 16 + quad * 4 + r] = accd[m][r];
    }
    __syncthreads();   // As reads done everywhere; denA visible

    // issue h staging now; completes at the next barrier (hidden under fold-1)
    stage_lin256(h, As, row0, wave, lane);

    // fold-1: acc = 0.5*(acc + N*v)/den   (no As use)
#pragma unroll
    for (int m = 0; m < 4; m++)
#pragma unroll
        for (int r = 0; r < 4; r++) {
            int rl = m * 16 + quad * 4 + r;
            float rden = 1.0f / (denA[rl] + Nf);
#pragma unroll
            for (int n = 0; n < 4; n++)
                acc[m][n][r] = 0.5f * (acc[m][n][r] + Nf * bf2f(vr[m][n][r])) * rden;
        }
    __syncthreads();   // h staged (barrier drains vmcnt)

    // fold-2: acc += 0.5*h ; LN stats
#pragma unroll
    for (int m = 0; m < 4; m++)
#pragma unroll
        for (int r = 0; r < 4; r++) {
            int rl = m * 16 + quad * 4 + r;
            float s = 0.f, s2 = 0.f;
#pragma unroll
            for (int n = 0; n < 4; n++) {
                int col = nb + n * 16 + l15;
                float pv = bf2f(As[(size_t)rl * 256 + col]);
                float val = acc[m][n][r] + 0.5f * pv;
                acc[m][n][r] = val;
                s += val; s2 += val * val;
            }
#pragma unroll
            for (int off = 1; off < 16; off <<= 1) {
                s += __shfl_xor(s, off);
                s2 += __shfl_xor(s2, off);
            }
            if (l15 == 0) { redS[rl][wave] = s; redQ[rl][wave] = s2; }
        }
    __syncthreads();   // all As (h) reads done; alias region now writable
    if (tid < 64) {
        float s = redS[tid][0] + redS[tid][1] + redS[tid][2] + redS[tid][3];
        float s2 = redQ[tid][0] + redQ[tid][1] + redQ[tid][2] + redQ[tid][3];
        float mean = s * (1.0f / 256.0f);
        float var = s2 * (1.0f / 256.0f) - mean * mean;
        rowm[tid] = mean;
        rowr[tid] = rsqrtf(var + EPSLN);
    }
    float g[4], bb[4];
#pragma unroll
    for (int n = 0; n < 4; n++) {
        g[n] = lng[nb + n * 16 + l15];
        bb[n] = lnb[nb + n * 16 + l15];
    }
#pragma unroll
    for (int m = 0; m < 4; ++m) {
        __syncthreads();   // m=0: rowm/rowr visible; m>0: prior drain done
#pragma unroll
        for (int n = 0; n < 4; ++n)
#pragma unroll
            for (int r = 0; r < 4; ++r) {
                int rl = m * 16 + quad * 4 + r;
                float x = (acc[m][n][r] - rowm[rl]) * rowr[rl] * g[n] + bb[n];
                Cb[(quad * 4 + r) * 256 + nb + n * 16 + l15] = f2bf(x);
            }
        __syncthreads();
#pragma unroll
        for (int ch = tid; ch < 512; ch += 256) {
            int rl = ch >> 5, co = (ch & 31) * 8;
            int row = row0 + m * 16 + rl;
            if (row < MROWS)
                *(short8*)(h + (size_t)row * 256 + co) = *(const short8*)&Cb[rl * 256 + co];
        }
    }
}

// ---------------------------------------------------------------------------
// Stage 0: h = relu(LN(x @ W_in + b_in)); x f32, K=512, slabbed KTILE=128.
// Double-buffered LDS slabs + reg-staged x prefetch + B register prefetch.
// ---------------------------------------------------------------------------
__global__ __launch_bounds__(256, 3)
void in_kernel(const float* __restrict__ x, const short* __restrict__ WinT,
               const float* __restrict__ b_in, const float* __restrict__ lng,
               const float* __restrict__ lnb, short* __restrict__ h)
{
    __shared__ short As[2][64 * 128];   // 2 x 16 KB
    __shared__ short Cb[16 * 264];
    __shared__ float redS[64][4], redQ[64][4];
    __shared__ float rowm[64], rowr[64];

    const int tid = threadIdx.x, wave = tid >> 6, lane = tid & 63;
    const int quad = lane >> 4, l15 = lane & 15;
    const int row0 = blockIdx.x * 64, nb = wave * 64;

    floatx4 acc[4][4];
#pragma unroll
    for (int m = 0; m < 4; m++)
#pragma unroll
        for (int n = 0; n < 4; n++) acc[m][n] = (floatx4)0.0f;

    floatx4 xr[4][2];
    auto issue = [&](int slab) {
#pragma unroll
        for (int it = 0; it < 4; ++it) {
            int J = it * 256 + tid;
            int row = J >> 4, jj = J & 15, c = jj ^ (row & 15);
            int rowg = min(row0 + row, MROWS - 1);
            const float* gp = x + (size_t)rowg * 512 + slab + c * 8;
            xr[it][0] = *(const floatx4*)gp;
            xr[it][1] = *(const floatx4*)(gp + 4);
        }
    };
    auto commit = [&](short* dst) {
#pragma unroll
        for (int it = 0; it < 4; ++it) {
            int J = it * 256 + tid;
            short8 s8;
#pragma unroll
            for (int i = 0; i < 4; ++i) { s8[i] = f2bf(xr[it][0][i]); s8[i + 4] = f2bf(xr[it][1][i]); }
            *(short8*)&dst[(size_t)J * 8] = s8;
        }
    };
    auto bload = [&](int s, int ki, int n) -> short8 {
        return *(const short8*)(WinT + (size_t)(nb + n * 16 + l15) * 512 + s * 128 + ki * 32 + quad * 8);
    };

    issue(0);
    commit(As[0]);
    __syncthreads();

#pragma unroll
    for (int s = 0; s < 4; ++s) {
        if (s < 3) issue((s + 1) * 128);          // x loads in flight under MFMAs
        const short* cur = As[s & 1];
        short8 bc[4];
#pragma unroll
        for (int n = 0; n < 4; ++n) bc[n] = bload(s, 0, n);
#pragma unroll
        for (int ki = 0; ki < 4; ++ki) {
            short8 bnx[4];
            if (ki < 3)
#pragma unroll
                for (int n = 0; n < 4; ++n) bnx[n] = bload(s, ki + 1, n);
            short8 a[4];
#pragma unroll
            for (int m = 0; m < 4; ++m) {
                int row = m * 16 + l15;
                int phys = (ki * 4 + quad) ^ (row & 15);
                a[m] = *(const short8*)&cur[((size_t)row * 16 + phys) * 8];
            }
#pragma unroll
            for (int n = 0; n < 4; ++n)
#pragma unroll
                for (int m = 0; m < 4; ++m)
                    acc[m][n] = __builtin_amdgcn_mfma_f32_16x16x32_bf16(a[m], bc[n], acc[m][n], 0, 0, 0);
            if (ki < 3)
#pragma unroll
                for (int n = 0; n < 4; ++n) bc[n] = bnx[n];
        }
        if (s < 3) {
            commit(As[(s + 1) & 1]);
            __syncthreads();
        }
    }
    // bias + LN stats
    float bn[4];
#pragma unroll
    for (int n = 0; n < 4; n++) bn[n] = b_in[nb + n * 16 + l15];
#pragma unroll
    for (int m = 0; m < 4; m++)
#pragma unroll
        for (int r = 0; r < 4; r++) {
            int rl = m * 16 + quad * 4 + r;
            float s = 0.f, s2 = 0.f;
#pragma unroll
            for (int n = 0; n < 4; n++) {
                float val = acc[m][n][r] + bn[n];
                acc[m][n][r] = val;
                s += val; s2 += val * val;
            }
#pragma unroll
            for (int off = 1; off < 16; off <<= 1) {
                s += __shfl_xor(s, off);
                s2 += __shfl_xor(s2, off);
            }
            if (l15 == 0) { redS[rl][wave] = s; redQ[rl][wave] = s2; }
        }
    __syncthreads();
    if (tid < 64) {
        float s = redS[tid][0] + redS[tid][1] + redS[tid][2] + redS[tid][3];
        float s2 = redQ[tid][0] + redQ[tid][1] + redQ[tid][2] + redQ[tid][3];
        float mean = s * (1.0f / 256.0f);
        float var = s2 * (1.0f / 256.0f) - mean * mean;
        rowm[tid] = mean;
        rowr[tid] = rsqrtf(var + EPSLN);
    }
    __syncthreads();
    float g[4], bb[4];
#pragma unroll
    for (int n = 0; n < 4; n++) {
        g[n] = lng[nb + n * 16 + l15];
        bb[n] = lnb[nb + n * 16 + l15];
    }
#pragma unroll
    for (int m = 0; m < 4; ++m) {
        __syncthreads();
#pragma unroll
        for (int n = 0; n < 4; ++n)
#pragma unroll
            for (int r = 0; r < 4; ++r) {
                int rl = m * 16 + quad * 4 + r;
                float xv = (acc[m][n][r] - rowm[rl]) * rowr[rl] * g[n] + bb[n];
                Cb[(quad * 4 + r) * 264 + nb + n * 16 + l15] = f2bf(fmaxf(xv, 0.f));
            }
        __syncthreads();
#pragma unroll
        for (int ch = tid; ch < 512; ch += 256) {
            int rl = ch >> 5, co = (ch & 31) * 8;
            int row = row0 + m * 16 + rl;
            if (row < MROWS)
                *(short8*)(h + (size_t)row * 256 + co) = *(const short8*)&Cb[rl * 264 + co];
        }
    }
}

// ---------------------------------------------------------------------------
// KV = k^T @ v  [256x256] f32, split over grid.z (224 x 7 blk64), frag input.
// Each 32-row stripe: frag-decode -> 8B ds_writes into transposed LDS tiles;
// next stripe register-prefetched under the MFMAs.
// ---------------------------------------------------------------------------
__global__ __launch_bounds__(256)
void kv_kernel(const short* __restrict__ kF, const short* __restrict__ vF,
               float* __restrict__ KV, int M)
{
    __shared__ short ksT[128][40];
    __shared__ short vsT[128][40];
    const int t = threadIdx.x, wave = t >> 6, lane = t & 63;
    const int quad = lane >> 4, l15 = lane & 15;
    const int mb = blockIdx.x * 128, nbb = blockIdx.y * 128;
    const int bbeg = blockIdx.z * 7;
    const int bend = min(GBLK, bbeg + 7);

    floatx4 acc[2][8];
#pragma unroll
    for (int m = 0; m < 2; m++)
#pragma unroll
        for (int j = 0; j < 8; j++) acc[m][j] = (floatx4)0.0f;

    const int wm = wave * 32;

    short4v kc[4], vc[4];
    auto loadstripe = [&](int blk, int half) {
#pragma unroll
        for (int i = 0; i < 4; ++i) {
            int ci = t + i * 256;
            int colc = ci & 127, rowg = ci >> 7;       // rowg in 0..7
            int qs = rowg & 3, mi = rowg >> 2;
            int m = half * 2 + mi;
            bool valid = (blk * 64 + m * 16 + qs * 4) < M;
            int Ck = mb + colc, Cv = nbb + colc;
            size_t ok = fragoff(blk, Ck >> 6, m, (Ck >> 4) & 3, qs * 16 + (Ck & 15)) * 4;
            size_t ov = fragoff(blk, Cv >> 6, m, (Cv >> 4) & 3, qs * 16 + (Cv & 15)) * 4;
            kc[i] = valid ? *(const short4v*)(kF + ok) : (short4v)(short)0;
            vc[i] = valid ? *(const short4v*)(vF + ov) : (short4v)(short)0;
        }
    };
    auto commit = [&]() {
#pragma unroll
        for (int i = 0; i < 4; ++i) {
            int ci = t + i * 256;
            int colc = ci & 127, rowg = ci >> 7;
            *(short4v*)&ksT[colc][rowg * 4] = kc[i];   // lr = mi*16+qs*4 = rowg*4
            *(short4v*)&vsT[colc][rowg * 4] = vc[i];
        }
    };

    loadstripe(bbeg, 0);
    for (int blk = bbeg; blk < bend; ++blk)
#pragma unroll
        for (int half = 0; half < 2; ++half) {
            __syncthreads();
            commit();
            __syncthreads();
            bool more = !(blk == bend - 1 && half == 1);
            if (more) loadstripe(half ? blk + 1 : blk, half ^ 1);   // prefetch
            short8 a0 = *(const short8*)&ksT[wm + l15][quad * 8];
            short8 a1 = *(const short8*)&ksT[wm + 16 + l15][quad * 8];
#pragma unroll
            for (int j = 0; j < 8; j++) {
                short8 b = *(const short8*)&vsT[j * 16 + l15][quad * 8];
                acc[0][j] = __builtin_amdgcn_mfma_f32_16x16x32_bf16(a0, b, acc[0][j], 0, 0, 0);
                acc[1][j] = __builtin_amdgcn_mfma_f32_16x16x32_bf16(a1, b, acc[1][j], 0, 0, 0);
            }
        }
#pragma unroll
    for (int mi = 0; mi < 2; mi++)
#pragma unroll
        for (int j = 0; j < 8; j++)
#pragma unroll
            for (int r = 0; r < 4; r++) {
                int m = mb + wm + mi * 16 + quad * 4 + r;
                int n = nbb + j * 16 + l15;
                atomicAdd(&KV[(size_t)m * HID + n], acc[mi][j][r]);
            }
}

// KVt[272][256]: rows 0..255 = (KV*s)^T bf16, row 256 = ksum*s, 257..271 = 0
__global__ void scale_kernel(const float* __restrict__ KV, const float* __restrict__ ksum,
                             const float* __restrict__ sq, short* __restrict__ KVt)
{
    float s = rsqrtf(sq[0]) * rsqrtf(sq[1]);
    int d = blockIdx.x;   // 0..271
    int m = threadIdx.x;  // 0..255
    float val;
    if (d < 256)       val = KV[(size_t)m * HID + d] * s;
    else if (d == 256) val = ksum[m] * s;
    else               val = 0.f;
    KVt[(size_t)d * HID + m] = f2bf(val);
}

// ---------------------------------------------------------------------------
// Final GEMM: Out[M,40] = h[M,256] @ W_out[256,40] + b_out
// ---------------------------------------------------------------------------
__global__ __launch_bounds__(256)
void gemm_out(const short* __restrict__ A, const short* __restrict__ BT,
              const float* __restrict__ bias, float* __restrict__ Out, int M)
{
    const int tid = threadIdx.x, wave = tid >> 6, lane = tid & 63;
    const int quad = lane >> 4, l15 = lane & 15;
    const int row0 = blockIdx.x * 128 + wave * 32;
    const int K = 256;
    floatx4 acc[2][3];
#pragma unroll
    for (int m = 0; m < 2; m++)
#pragma unroll
        for (int n = 0; n < 3; n++) acc[m][n] = (floatx4)0.0f;

    int ra0 = min(row0 + l15, M - 1);
    int ra1 = min(row0 + 16 + l15, M - 1);
    for (int kk = 0; kk < K; kk += 32) {
        short8 a0 = *(const short8*)(A + (size_t)ra0 * K + kk + quad * 8);
        short8 a1 = *(const short8*)(A + (size_t)ra1 * K + kk + quad * 8);
#pragma unroll
        for (int n = 0; n < 3; n++) {
            int col = n * 16 + l15;
            short8 b = (short8)(short)0;
            if (col < 40) b = *(const short8*)(BT + (size_t)col * K + kk + quad * 8);
            acc[0][n] = __builtin_amdgcn_mfma_f32_16x16x32_bf16(a0, b, acc[0][n], 0, 0, 0);
            acc[1][n] = __builtin_amdgcn_mfma_f32_16x16x32_bf16(a1, b, acc[1][n], 0, 0, 0);
        }
    }
#pragma unroll
    for (int m = 0; m < 2; m++)
#pragma unroll
        for (int n = 0; n < 3; n++)
#pragma unroll
            for (int r = 0; r < 4; r++) {
                int row = row0 + m * 16 + quad * 4 + r;
                int col = n * 16 + l15;
                if (row < M && col < 40)
                    Out[(size_t)row * 40 + col] = acc[m][n][r] + bias[col];
            }
}

// --------------------------- small utility kernels -------------------------
struct TJobs { const float* src[8]; short* dst[8]; int R[8]; int C[8]; };

__global__ void wtrans(TJobs j)  // dst[C][R] = bf16(src[R][C])
{
    int job = blockIdx.y;
    int R = j.R[job], Cc = j.C[job];
    const float* s = j.src[job];
    short* d = j.dst[job];
    int n = R * Cc;
    for (int idx = blockIdx.x * 256 + threadIdx.x; idx < n; idx += gridDim.x * 256) {
        int r = idx / Cc, c = idx - r * Cc;
        d[(size_t)c * R + r] = f2bf(s[idx]);
    }
}

__global__ void zerof(float* p, int n)
{
    int i = blockIdx.x * 256 + threadIdx.x;
    if (i < n) p[i] = 0.f;
}

// ---------------------------------------------------------------------------
extern "C" void kernel_launch(void* const* d_in, const int* in_sizes, int n_in,
                              void* d_out, int out_size, void* d_ws, size_t ws_size,
                              hipStream_t stream)
{
    const float* x    = (const float*)d_in[0];
    // d_in[1] = edge_index: unused (use_graph=False)
    const float* W_in = (const float*)d_in[2];
    const float* b_in = (const float*)d_in[3];
    const float* ln0g = (const float*)d_in[4];
    const float* ln0b = (const float*)d_in[5];
    const float* Wq0  = (const float*)d_in[6];  const float* bq0 = (const float*)d_in[7];
    const float* Wk0  = (const float*)d_in[8];  const float* bk0 = (const float*)d_in[9];
    const float* Wv0  = (const float*)d_in[10]; const float* bv0 = (const float*)d_in[11];
    const float* ln1g = (const float*)d_in[12]; const float* ln1b = (const float*)d_in[13];
    const float* Wq1  = (const float*)d_in[14]; const float* bq1 = (const float*)d_in[15];
    const float* Wk1  = (const float*)d_in[16]; const float* bk1 = (const float*)d_in[17];
    const float* Wv1  = (const float*)d_in[18]; const float* bv1 = (const float*)d_in[19];
    const float* ln2g = (const float*)d_in[20]; const float* ln2b = (const float*)d_in[21];
    const float* W_out = (const float*)d_in[22]; const float* b_out = (const float*)d_in[23];

    const int M = MROWS;
    const int MPAD = GBLK * 64;           // 100032
    char* ws = (char*)d_ws;
    size_t off = 0;
    auto alloc = [&](size_t bytes) -> char* {
        char* p = ws + off;
        off += (bytes + 255) & ~(size_t)255;
        return p;
    };
    short* h = (short*)alloc((size_t)M * HID * 2);
    short* q = (short*)alloc((size_t)M * HID * 2);
    short* k = (short*)alloc((size_t)MPAD * HID * 2);   // fragment layout
    short* v = (short*)alloc((size_t)MPAD * HID * 2);   // fragment layout
    short* WinT  = (short*)alloc((size_t)512 * 256 * 2);
    short* WqT0  = (short*)alloc((size_t)65536 * 2);
    short* WkT0  = (short*)alloc((size_t)65536 * 2);
    short* WvT0  = (short*)alloc((size_t)65536 * 2);
    short* WqT1  = (short*)alloc((size_t)65536 * 2);
    short* WkT1  = (short*)alloc((size_t)65536 * 2);
    short* WvT1  = (short*)alloc((size_t)65536 * 2);
    short* WoutT = (short*)alloc((size_t)40 * 256 * 2);
    float* zbase = (float*)alloc((size_t)(65536 * 2 + 256 * 2 + 4) * 4);
    float* KV0 = zbase;
    float* KV1 = zbase + 65536;
    float* ksum0 = zbase + 131072;
    float* ksum1 = ksum0 + 256;
    float* sq = ksum1 + 256;  // [sq_q0, sq_k0, sq_q1, sq_k1]
    short* KVt0 = (short*)alloc((size_t)272 * 256 * 2);
    short* KVt1 = (short*)alloc((size_t)272 * 256 * 2);

    const int ZN = 65536 * 2 + 256 * 2 + 4;
    zerof<<<dim3((ZN + 255) / 256), 256, 0, stream>>>(zbase, ZN);

    TJobs tj;
    tj.src[0] = W_in;  tj.dst[0] = WinT;  tj.R[0] = 512; tj.C[0] = 256;
    tj.src[1] = Wq0;   tj.dst[1] = WqT0;  tj.R[1] = 256; tj.C[1] = 256;
    tj.src[2] = Wk0;   tj.dst[2] = WkT0;  tj.R[2] = 256; tj.C[2] = 256;
    tj.src[3] = Wv0;   tj.dst[3] = WvT0;  tj.R[3] = 256; tj.C[3] = 256;
    tj.src[4] = Wq1;   tj.dst[4] = WqT1;  tj.R[4] = 256; tj.C[4] = 256;
    tj.src[5] = Wk1;   tj.dst[5] = WkT1;  tj.R[5] = 256; tj.C[5] = 256;
    tj.src[6] = Wv1;   tj.dst[6] = WvT1;  tj.R[6] = 256; tj.C[6] = 256;
    tj.src[7] = W_out; tj.dst[7] = WoutT; tj.R[7] = 256; tj.C[7] = 40;
    wtrans<<<dim3(512, 8), 256, 0, stream>>>(tj);

    const int GB = GBLK;
    const float Nf = (float)M;
    const int ZB = (GBLK + 6) / 7;        // 224

    in_kernel<<<GB, 256, 0, stream>>>(x, WinT, b_in, ln0g, ln0b, h);
    // ---- layer 0 ----
    qkv_kernel<<<GB, 256, 0, stream>>>(h, WqT0, WkT0, WvT0, bq0, bk0, bv0,
                                       q, k, v, sq + 0, sq + 1, ksum0);
    kv_kernel<<<dim3(2, 2, ZB), 256, 0, stream>>>(k, v, KV0, M);
    scale_kernel<<<272, 256, 0, stream>>>(KV0, ksum0, sq + 0, KVt0);
    attn_kernel<<<GB, 256, 0, stream>>>(q, KVt0, v, h, ln1g, ln1b, Nf);
    // ---- layer 1 ----
    qkv_kernel<<<GB, 256, 0, stream>>>(h, WqT1, WkT1, WvT1, bq1, bk1, bv1,
                                       q, k, v, sq + 2, sq + 3, ksum1);
    kv_kernel<<<dim3(2, 2, ZB), 256, 0, stream>>>(k, v, KV1, M);
    scale_kernel<<<272, 256, 0, stream>>>(KV1, ksum1, sq + 2, KVt1);
    attn_kernel<<<GB, 256, 0, stream>>>(q, KVt1, v, h, ln2g, ln2b, Nf);
    // ---- output ----
    gemm_out<<<(M + 127) / 128, 256, 0, stream>>>(h, WoutT, b_out, (float*)d_out, M);
}

// Round 3
// 1142.796 us; speedup vs baseline: 1.1136x; 1.1136x over previous
//
#include <hip/hip_runtime.h>

// ---------------------------------------------------------------------------
// SGFormer forward, MI355X/gfx950.  I/O f32; internal h/q/k/v bf16.
// attn = (q @ (k^T v) * s + N*v) / (q . (sum_k) * s + N),  s = 1/(||q|| ||k||)
// KVt[272][256]: rows 0..255 = (KV*s)^T, row 256 = ksum*s, 257..271 = 0.
//
// R6 lesson (counters): launch_bounds(256,4) + B-prefetch regs -> spills
// (FETCH 34->128MB, WRITE 161->373MB = scratch traffic); Cb stride 256 ->
// 800K LDS bank conflicts.  R7 (this round): bounds back to (256,3), no B
// double-buffer (compiler pipelines the unrolled loop), Cb stride 264.
// Keep: k,v in MFMA C-fragment layout (qkv stores barrier-free; attn reads
// v with identical mapping; kv decodes frags), shfl+atomic reductions,
// attn h-stage overlap + LDS aliasing, in_kernel xr slab double-buffer.
// ---------------------------------------------------------------------------

typedef __attribute__((ext_vector_type(8))) short short8;
typedef __attribute__((ext_vector_type(4))) short short4v;
typedef __attribute__((ext_vector_type(4))) float floatx4;

__device__ __forceinline__ float bf2f(short u) {
    union { unsigned int i; float f; } v;
    v.i = ((unsigned int)(unsigned short)u) << 16;
    return v.f;
}
__device__ __forceinline__ short f2bf(float f) {
    union { float f; unsigned int i; } v; v.f = f;
    unsigned int b = v.i + 0x7fffu + ((v.i >> 16) & 1u);  // RNE
    return (short)(b >> 16);
}

#define HID 256
#define MROWS 100000
#define GBLK 1563            // ceil(MROWS/64)
#define EPSLN 1e-5f

// C-fragment layout: unit = 4 shorts (8B) = rows {m*16+quad*4+0..3}, col
// nb + n*16 + l15, for (blk, wave, m, n, lane).  One store inst = 512B.
__device__ __forceinline__ size_t fragoff(int blk, int w, int m, int n, int lane) {
    return (((((size_t)blk * 4 + w) * 4 + m) * 4 + n) * 64 + lane);
}

// ---- stage a 64x256 bf16 A-tile into LDS via global_load_lds, XOR-swizzled.
__device__ __forceinline__ void stage_a256(const short* __restrict__ A, short* As,
                                           int row0, int wave, int lane)
{
    const int base = wave * 512;
#pragma unroll
    for (int it = 0; it < 8; ++it) {
        int J = base + it * 64 + lane;
        int row = J >> 5, jj = J & 31;
        int c = jj ^ (row & 31);
        int rowg = min(row0 + row, MROWS - 1);
        const short* gp = A + (size_t)rowg * HID + c * 8;
        __builtin_amdgcn_global_load_lds(
            (const __attribute__((address_space(1))) void*)gp,
            (__attribute__((address_space(3))) void*)&As[(size_t)(base + it * 64) * 8],
            16, 0, 0);
    }
}
// ---- same, linear (no swizzle): for tiles read scalar later.
__device__ __forceinline__ void stage_lin256(const short* __restrict__ A, short* As,
                                             int row0, int wave, int lane)
{
    const int base = wave * 512;
#pragma unroll
    for (int it = 0; it < 8; ++it) {
        int J = base + it * 64 + lane;
        int row = J >> 5, jj = J & 31;
        int rowg = min(row0 + row, MROWS - 1);
        const short* gp = A + (size_t)rowg * HID + jj * 8;
        __builtin_amdgcn_global_load_lds(
            (const __attribute__((address_space(1))) void*)gp,
            (__attribute__((address_space(3))) void*)&As[(size_t)(base + it * 64) * 8],
            16, 0, 0);
    }
}
__device__ __forceinline__ short8 read_a256(const short* As, int m, int ki, int quad, int l15)
{
    int row = m * 16 + l15;
    int phys = (ki * 4 + quad) ^ (row & 31);
    return *(const short8*)&As[((size_t)row * 32 + phys) * 8];
}

// ---------------------------------------------------------------------------
// Fused q/k/v projection.  k,v -> fragment layout (no barriers); q -> bounced
// row-major.  Frobenius sumsq for q,k and column-sum for k via shfl+atomics.
// ---------------------------------------------------------------------------
__global__ __launch_bounds__(256, 3)
void qkv_kernel(const short* __restrict__ h,
                const short* __restrict__ BTq, const short* __restrict__ BTk,
                const short* __restrict__ BTv,
                const float* __restrict__ bq, const float* __restrict__ bk,
                const float* __restrict__ bv,
                short* __restrict__ qO, short* __restrict__ kF, short* __restrict__ vF,
                float* __restrict__ sqq, float* __restrict__ sqk,
                float* __restrict__ ksum)
{
    __shared__ short As[64 * 256];      // 32 KB
    __shared__ short Cb[16 * 264];      // 8.25 KB (pad +8: row stride 132 dw)

    const int tid = threadIdx.x, wave = tid >> 6, lane = tid & 63;
    const int quad = lane >> 4, l15 = lane & 15;
    const int blk = blockIdx.x;
    const int row0 = blk * 64, nb = wave * 64;

    stage_a256(h, As, row0, wave, lane);
    __syncthreads();

    floatx4 acc[4][4];

    auto gemm256 = [&](const short* __restrict__ BT) {
#pragma unroll
        for (int m = 0; m < 4; m++)
#pragma unroll
            for (int n = 0; n < 4; n++) acc[m][n] = (floatx4)0.0f;
#pragma unroll
        for (int ki = 0; ki < 8; ++ki) {
            short8 a[4];
#pragma unroll
            for (int m = 0; m < 4; ++m) a[m] = read_a256(As, m, ki, quad, l15);
#pragma unroll
            for (int n = 0; n < 4; ++n) {
                short8 b = *(const short8*)(BT + (size_t)(nb + n * 16 + l15) * 256 + ki * 32 + quad * 8);
#pragma unroll
                for (int m = 0; m < 4; ++m)
                    acc[m][n] = __builtin_amdgcn_mfma_f32_16x16x32_bf16(a[m], b, acc[m][n], 0, 0, 0);
            }
        }
    };

    float bn[4];

    // ---------------- K ----------------
    gemm256(BTk);
#pragma unroll
    for (int n = 0; n < 4; n++) bn[n] = bk[nb + n * 16 + l15];
    {
        float ssq = 0.f;
        float csum[4] = {0.f, 0.f, 0.f, 0.f};
#pragma unroll
        for (int m = 0; m < 4; m++)
#pragma unroll
            for (int r = 0; r < 4; r++) {
                int rl = m * 16 + quad * 4 + r;
                bool valid = (row0 + rl) < MROWS;
#pragma unroll
                for (int n = 0; n < 4; n++) {
                    float val = acc[m][n][r] + bn[n];
                    acc[m][n][r] = val;
                    if (valid) { ssq += val * val; csum[n] += val; }
                }
            }
#pragma unroll
        for (int off = 32; off; off >>= 1) ssq += __shfl_down(ssq, off);
        if (lane == 0) atomicAdd(sqk, ssq);
#pragma unroll
        for (int n = 0; n < 4; n++) {
            float cv = csum[n];
            cv += __shfl_xor(cv, 16);
            cv += __shfl_xor(cv, 32);
            if (quad == 0) atomicAdd(&ksum[nb + n * 16 + l15], cv);
        }
#pragma unroll
        for (int m = 0; m < 4; ++m)
#pragma unroll
            for (int n = 0; n < 4; ++n) {
                short4v s4;
#pragma unroll
                for (int r = 0; r < 4; ++r) s4[r] = f2bf(acc[m][n][r]);
                *(short4v*)(kF + fragoff(blk, wave, m, n, lane) * 4) = s4;
            }
    }

    // ---------------- V ----------------
    gemm256(BTv);
#pragma unroll
    for (int n = 0; n < 4; n++) bn[n] = bv[nb + n * 16 + l15];
#pragma unroll
    for (int m = 0; m < 4; ++m)
#pragma unroll
        for (int n = 0; n < 4; ++n) {
            short4v s4;
#pragma unroll
            for (int r = 0; r < 4; ++r) s4[r] = f2bf(acc[m][n][r] + bn[n]);
            *(short4v*)(vF + fragoff(blk, wave, m, n, lane) * 4) = s4;
        }

    // ---------------- Q ----------------
    gemm256(BTq);
#pragma unroll
    for (int n = 0; n < 4; n++) bn[n] = bq[nb + n * 16 + l15];
    {
        float ssq = 0.f;
#pragma unroll
        for (int m = 0; m < 4; m++)
#pragma unroll
            for (int r = 0; r < 4; r++) {
                int rl = m * 16 + quad * 4 + r;
                bool valid = (row0 + rl) < MROWS;
#pragma unroll
                for (int n = 0; n < 4; n++) {
                    float val = acc[m][n][r] + bn[n];
                    acc[m][n][r] = val;
                    if (valid) ssq += val * val;
                }
            }
#pragma unroll
        for (int off = 32; off; off >>= 1) ssq += __shfl_down(ssq, off);
        if (lane == 0) atomicAdd(sqq, ssq);
    }
    // bounce q row-major (coalesced 512B lines)
#pragma unroll
    for (int m = 0; m < 4; ++m) {
        __syncthreads();
#pragma unroll
        for (int n = 0; n < 4; ++n)
#pragma unroll
            for (int r = 0; r < 4; ++r)
                Cb[(quad * 4 + r) * 264 + nb + n * 16 + l15] = f2bf(acc[m][n][r]);
        __syncthreads();
#pragma unroll
        for (int ch = tid; ch < 512; ch += 256) {
            int rl = ch >> 5, co = (ch & 31) * 8;
            int row = row0 + m * 16 + rl;
            if (row < MROWS)
                *(short8*)(qO + (size_t)row * 256 + co) = *(const short8*)&Cb[rl * 264 + co];
        }
    }
}

// ---------------------------------------------------------------------------
// Attention epilogue GEMM: acc = q @ KVt_s (den col = KVt row 256, wave 0);
// h = 0.5*(acc + N*v)/den + 0.5*h; LayerNorm; in-place.
// v read directly in fragment layout (16x 8B loads, same mapping as qkv's
// acc).  h staged into As (dead after MFMA) while fold-1 computes.
// Cb / rowm / rowr aliased into As -> 35 KB LDS.
// ---------------------------------------------------------------------------
__global__ __launch_bounds__(256, 3)
void attn_kernel(const short* __restrict__ q, const short* __restrict__ KVt,
                 const short* __restrict__ vF, short* __restrict__ h,
                 const float* __restrict__ lng, const float* __restrict__ lnb,
                 float Nf)
{
    __shared__ short As[64 * 256];      // 32 KB
    __shared__ float denA[64];
    __shared__ float redS[64][4], redQ[64][4];
    short* Cb = As;                     // alias: bytes [0, 8448) stride 264
    float* rowm = (float*)&As[4352];    // bytes [8704, 8960)
    float* rowr = (float*)&As[4480];    // bytes [8960, 9216)

    const int tid = threadIdx.x, wave = tid >> 6, lane = tid & 63;
    const int quad = lane >> 4, l15 = lane & 15;
    const int blk = blockIdx.x;
    const int row0 = blk * 64, nb = wave * 64;

    stage_a256(q, As, row0, wave, lane);
    __syncthreads();

    floatx4 acc[4][4];
#pragma unroll
    for (int m = 0; m < 4; m++)
#pragma unroll
        for (int n = 0; n < 4; n++) acc[m][n] = (floatx4)0.0f;
    floatx4 accd[4];
#pragma unroll
    for (int m = 0; m < 4; m++) accd[m] = (floatx4)0.0f;

#pragma unroll
    for (int ki = 0; ki < 8; ++ki) {
        short8 a[4];
#pragma unroll
        for (int m = 0; m < 4; ++m) a[m] = read_a256(As, m, ki, quad, l15);
#pragma unroll
        for (int n = 0; n < 4; ++n) {
            short8 b = *(const short8*)(KVt + (size_t)(nb + n * 16 + l15) * 256 + ki * 32 + quad * 8);
#pragma unroll
            for (int m = 0; m < 4; ++m)
                acc[m][n] = __builtin_amdgcn_mfma_f32_16x16x32_bf16(a[m], b, acc[m][n], 0, 0, 0);
        }
        if (wave == 0) {
            short8 bd = *(const short8*)(KVt + (size_t)(256 + l15) * 256 + ki * 32 + quad * 8);
#pragma unroll
            for (int m = 0; m < 4; ++m)
                accd[m] = __builtin_amdgcn_mfma_f32_16x16x32_bf16(a[m], bd, accd[m], 0, 0, 0);
        }
    }
    // v fragment loads (independent; latency hidden under denA + fold-1 setup)
    short4v vr[4][4];
#pragma unroll
    for (int m = 0; m < 4; ++m)
#pragma unroll
        for (int n = 0; n < 4; ++n)
            vr[m][n] = *(const short4v*)(vF + fragoff(blk, wave, m, n, lane) * 4);

    if (wave == 0 && l15 == 0) {
#pragma unroll
        for (int m = 0; m < 4; m++)
#pragma unroll
            for (int r = 0; r < 4; r++)
                denA[m * 16 + quad * 4 + r] = accd[m][r];
    }
    __syncthreads();   // As reads done everywhere; denA visible

    // issue h staging now; completes at the next barrier (hidden under fold-1)
    stage_lin256(h, As, row0, wave, lane);

    // fold-1: acc = 0.5*(acc + N*v)/den   (no As use)
#pragma unroll
    for (int m = 0; m < 4; m++)
#pragma unroll
        for (int r = 0; r < 4; r++) {
            int rl = m * 16 + quad * 4 + r;
            float rden = 1.0f / (denA[rl] + Nf);
#pragma unroll
            for (int n = 0; n < 4; n++)
                acc[m][n][r] = 0.5f * (acc[m][n][r] + Nf * bf2f(vr[m][n][r])) * rden;
        }
    __syncthreads();   // h staged (barrier drains vmcnt)

    // fold-2: acc += 0.5*h ; LN stats
#pragma unroll
    for (int m = 0; m < 4; m++)
#pragma unroll
        for (int r = 0; r < 4; r++) {
            int rl = m * 16 + quad * 4 + r;
            float s = 0.f, s2 = 0.f;
#pragma unroll
            for (int n = 0; n < 4; n++) {
                int col = nb + n * 16 + l15;
                float pv = bf2f(As[(size_t)rl * 256 + col]);
                float val = acc[m][n][r] + 0.5f * pv;
                acc[m][n][r] = val;
                s += val; s2 += val * val;
            }
#pragma unroll
            for (int off = 1; off < 16; off <<= 1) {
                s += __shfl_xor(s, off);
                s2 += __shfl_xor(s2, off);
            }
            if (l15 == 0) { redS[rl][wave] = s; redQ[rl][wave] = s2; }
        }
    __syncthreads();   // all As (h) reads done; alias region now writable
    if (tid < 64) {
        float s = redS[tid][0] + redS[tid][1] + redS[tid][2] + redS[tid][3];
        float s2 = redQ[tid][0] + redQ[tid][1] + redQ[tid][2] + redQ[tid][3];
        float mean = s * (1.0f / 256.0f);
        float var = s2 * (1.0f / 256.0f) - mean * mean;
        rowm[tid] = mean;
        rowr[tid] = rsqrtf(var + EPSLN);
    }
    float g[4], bb[4];
#pragma unroll
    for (int n = 0; n < 4; n++) {
        g[n] = lng[nb + n * 16 + l15];
        bb[n] = lnb[nb + n * 16 + l15];
    }
#pragma unroll
    for (int m = 0; m < 4; ++m) {
        __syncthreads();   // m=0: rowm/rowr visible; m>0: prior drain done
#pragma unroll
        for (int n = 0; n < 4; ++n)
#pragma unroll
            for (int r = 0; r < 4; ++r) {
                int rl = m * 16 + quad * 4 + r;
                float x = (acc[m][n][r] - rowm[rl]) * rowr[rl] * g[n] + bb[n];
                Cb[(quad * 4 + r) * 264 + nb + n * 16 + l15] = f2bf(x);
            }
        __syncthreads();
#pragma unroll
        for (int ch = tid; ch < 512; ch += 256) {
            int rl = ch >> 5, co = (ch & 31) * 8;
            int row = row0 + m * 16 + rl;
            if (row < MROWS)
                *(short8*)(h + (size_t)row * 256 + co) = *(const short8*)&Cb[rl * 264 + co];
        }
    }
}

// ---------------------------------------------------------------------------
// Stage 0: h = relu(LN(x @ W_in + b_in)); x f32, K=512, slabbed KTILE=128.
// Double-buffered LDS slabs + reg-staged x prefetch.
// ---------------------------------------------------------------------------
__global__ __launch_bounds__(256, 3)
void in_kernel(const float* __restrict__ x, const short* __restrict__ WinT,
               const float* __restrict__ b_in, const float* __restrict__ lng,
               const float* __restrict__ lnb, short* __restrict__ h)
{
    __shared__ short As[2][64 * 128];   // 2 x 16 KB
    __shared__ short Cb[16 * 264];
    __shared__ float redS[64][4], redQ[64][4];
    __shared__ float rowm[64], rowr[64];

    const int tid = threadIdx.x, wave = tid >> 6, lane = tid & 63;
    const int quad = lane >> 4, l15 = lane & 15;
    const int row0 = blockIdx.x * 64, nb = wave * 64;

    floatx4 acc[4][4];
#pragma unroll
    for (int m = 0; m < 4; m++)
#pragma unroll
        for (int n = 0; n < 4; n++) acc[m][n] = (floatx4)0.0f;

    floatx4 xr[4][2];
    auto issue = [&](int slab) {
#pragma unroll
        for (int it = 0; it < 4; ++it) {
            int J = it * 256 + tid;
            int row = J >> 4, jj = J & 15, c = jj ^ (row & 15);
            int rowg = min(row0 + row, MROWS - 1);
            const float* gp = x + (size_t)rowg * 512 + slab + c * 8;
            xr[it][0] = *(const floatx4*)gp;
            xr[it][1] = *(const floatx4*)(gp + 4);
        }
    };
    auto commit = [&](short* dst) {
#pragma unroll
        for (int it = 0; it < 4; ++it) {
            int J = it * 256 + tid;
            short8 s8;
#pragma unroll
            for (int i = 0; i < 4; ++i) { s8[i] = f2bf(xr[it][0][i]); s8[i + 4] = f2bf(xr[it][1][i]); }
            *(short8*)&dst[(size_t)J * 8] = s8;
        }
    };

    issue(0);
    commit(As[0]);
    __syncthreads();

#pragma unroll
    for (int s = 0; s < 4; ++s) {
        if (s < 3) issue((s + 1) * 128);          // x loads in flight under MFMAs
        const short* cur = As[s & 1];
#pragma unroll
        for (int ki = 0; ki < 4; ++ki) {
            short8 a[4];
#pragma unroll
            for (int m = 0; m < 4; ++m) {
                int row = m * 16 + l15;
                int phys = (ki * 4 + quad) ^ (row & 15);
                a[m] = *(const short8*)&cur[((size_t)row * 16 + phys) * 8];
            }
#pragma unroll
            for (int n = 0; n < 4; ++n) {
                short8 b = *(const short8*)(WinT + (size_t)(nb + n * 16 + l15) * 512 + s * 128 + ki * 32 + quad * 8);
#pragma unroll
                for (int m = 0; m < 4; ++m)
                    acc[m][n] = __builtin_amdgcn_mfma_f32_16x16x32_bf16(a[m], b, acc[m][n], 0, 0, 0);
            }
        }
        if (s < 3) {
            commit(As[(s + 1) & 1]);
            __syncthreads();
        }
    }
    // bias + LN stats
    float bn[4];
#pragma unroll
    for (int n = 0; n < 4; n++) bn[n] = b_in[nb + n * 16 + l15];
#pragma unroll
    for (int m = 0; m < 4; m++)
#pragma unroll
        for (int r = 0; r < 4; r++) {
            int rl = m * 16 + quad * 4 + r;
            float s = 0.f, s2 = 0.f;
#pragma unroll
            for (int n = 0; n < 4; n++) {
                float val = acc[m][n][r] + bn[n];
                acc[m][n][r] = val;
                s += val; s2 += val * val;
            }
#pragma unroll
            for (int off = 1; off < 16; off <<= 1) {
                s += __shfl_xor(s, off);
                s2 += __shfl_xor(s2, off);
            }
            if (l15 == 0) { redS[rl][wave] = s; redQ[rl][wave] = s2; }
        }
    __syncthreads();
    if (tid < 64) {
        float s = redS[tid][0] + redS[tid][1] + redS[tid][2] + redS[tid][3];
        float s2 = redQ[tid][0] + redQ[tid][1] + redQ[tid][2] + redQ[tid][3];
        float mean = s * (1.0f / 256.0f);
        float var = s2 * (1.0f / 256.0f) - mean * mean;
        rowm[tid] = mean;
        rowr[tid] = rsqrtf(var + EPSLN);
    }
    __syncthreads();
    float g[4], bb[4];
#pragma unroll
    for (int n = 0; n < 4; n++) {
        g[n] = lng[nb + n * 16 + l15];
        bb[n] = lnb[nb + n * 16 + l15];
    }
#pragma unroll
    for (int m = 0; m < 4; ++m) {
        __syncthreads();
#pragma unroll
        for (int n = 0; n < 4; ++n)
#pragma unroll
            for (int r = 0; r < 4; ++r) {
                int rl = m * 16 + quad * 4 + r;
                float xv = (acc[m][n][r] - rowm[rl]) * rowr[rl] * g[n] + bb[n];
                Cb[(quad * 4 + r) * 264 + nb + n * 16 + l15] = f2bf(fmaxf(xv, 0.f));
            }
        __syncthreads();
#pragma unroll
        for (int ch = tid; ch < 512; ch += 256) {
            int rl = ch >> 5, co = (ch & 31) * 8;
            int row = row0 + m * 16 + rl;
            if (row < MROWS)
                *(short8*)(h + (size_t)row * 256 + co) = *(const short8*)&Cb[rl * 264 + co];
        }
    }
}

// ---------------------------------------------------------------------------
// KV = k^T @ v  [256x256] f32, split over grid.z (224 x 7 blk64), frag input.
// Each 32-row stripe: frag-decode -> 8B ds_writes into transposed LDS tiles;
// next stripe register-prefetched under the MFMAs.
// ---------------------------------------------------------------------------
__global__ __launch_bounds__(256)
void kv_kernel(const short* __restrict__ kF, const short* __restrict__ vF,
               float* __restrict__ KV, int M)
{
    __shared__ short ksT[128][40];
    __shared__ short vsT[128][40];
    const int t = threadIdx.x, wave = t >> 6, lane = t & 63;
    const int quad = lane >> 4, l15 = lane & 15;
    const int mb = blockIdx.x * 128, nbb = blockIdx.y * 128;
    const int bbeg = blockIdx.z * 7;
    const int bend = min(GBLK, bbeg + 7);

    floatx4 acc[2][8];
#pragma unroll
    for (int m = 0; m < 2; m++)
#pragma unroll
        for (int j = 0; j < 8; j++) acc[m][j] = (floatx4)0.0f;

    const int wm = wave * 32;

    short4v kc[4], vc[4];
    auto loadstripe = [&](int blk, int half) {
#pragma unroll
        for (int i = 0; i < 4; ++i) {
            int ci = t + i * 256;
            int colc = ci & 127, rowg = ci >> 7;       // rowg in 0..7
            int qs = rowg & 3, mi = rowg >> 2;
            int m = half * 2 + mi;
            bool valid = (blk * 64 + m * 16 + qs * 4) < M;
            int Ck = mb + colc, Cv = nbb + colc;
            size_t ok = fragoff(blk, Ck >> 6, m, (Ck >> 4) & 3, qs * 16 + (Ck & 15)) * 4;
            size_t ov = fragoff(blk, Cv >> 6, m, (Cv >> 4) & 3, qs * 16 + (Cv & 15)) * 4;
            kc[i] = valid ? *(const short4v*)(kF + ok) : (short4v)(short)0;
            vc[i] = valid ? *(const short4v*)(vF + ov) : (short4v)(short)0;
        }
    };
    auto commit = [&]() {
#pragma unroll
        for (int i = 0; i < 4; ++i) {
            int ci = t + i * 256;
            int colc = ci & 127, rowg = ci >> 7;
            *(short4v*)&ksT[colc][rowg * 4] = kc[i];   // lr = mi*16+qs*4 = rowg*4
            *(short4v*)&vsT[colc][rowg * 4] = vc[i];
        }
    };

    loadstripe(bbeg, 0);
    for (int blk = bbeg; blk < bend; ++blk)
#pragma unroll
        for (int half = 0; half < 2; ++half) {
            __syncthreads();
            commit();
            __syncthreads();
            bool more = !(blk == bend - 1 && half == 1);
            short8 a0 = *(const short8*)&ksT[wm + l15][quad * 8];
            short8 a1 = *(const short8*)&ksT[wm + 16 + l15][quad * 8];
            if (more) loadstripe(half ? blk + 1 : blk, half ^ 1);   // prefetch
#pragma unroll
            for (int j = 0; j < 8; j++) {
                short8 b = *(const short8*)&vsT[j * 16 + l15][quad * 8];
                acc[0][j] = __builtin_amdgcn_mfma_f32_16x16x32_bf16(a0, b, acc[0][j], 0, 0, 0);
                acc[1][j] = __builtin_amdgcn_mfma_f32_16x16x32_bf16(a1, b, acc[1][j], 0, 0, 0);
            }
        }
#pragma unroll
    for (int mi = 0; mi < 2; mi++)
#pragma unroll
        for (int j = 0; j < 8; j++)
#pragma unroll
            for (int r = 0; r < 4; r++) {
                int m = mb + wm + mi * 16 + quad * 4 + r;
                int n = nbb + j * 16 + l15;
                atomicAdd(&KV[(size_t)m * HID + n], acc[mi][j][r]);
            }
}

// KVt[272][256]: rows 0..255 = (KV*s)^T bf16, row 256 = ksum*s, 257..271 = 0
__global__ void scale_kernel(const float* __restrict__ KV, const float* __restrict__ ksum,
                             const float* __restrict__ sq, short* __restrict__ KVt)
{
    float s = rsqrtf(sq[0]) * rsqrtf(sq[1]);
    int d = blockIdx.x;   // 0..271
    int m = threadIdx.x;  // 0..255
    float val;
    if (d < 256)       val = KV[(size_t)m * HID + d] * s;
    else if (d == 256) val = ksum[m] * s;
    else               val = 0.f;
    KVt[(size_t)d * HID + m] = f2bf(val);
}

// ---------------------------------------------------------------------------
// Final GEMM: Out[M,40] = h[M,256] @ W_out[256,40] + b_out
// ---------------------------------------------------------------------------
__global__ __launch_bounds__(256)
void gemm_out(const short* __restrict__ A, const short* __restrict__ BT,
              const float* __restrict__ bias, float* __restrict__ Out, int M)
{
    const int tid = threadIdx.x, wave = tid >> 6, lane = tid & 63;
    const int quad = lane >> 4, l15 = lane & 15;
    const int row0 = blockIdx.x * 128 + wave * 32;
    const int K = 256;
    floatx4 acc[2][3];
#pragma unroll
    for (int m = 0; m < 2; m++)
#pragma unroll
        for (int n = 0; n < 3; n++) acc[m][n] = (floatx4)0.0f;

    int ra0 = min(row0 + l15, M - 1);
    int ra1 = min(row0 + 16 + l15, M - 1);
    for (int kk = 0; kk < K; kk += 32) {
        short8 a0 = *(const short8*)(A + (size_t)ra0 * K + kk + quad * 8);
        short8 a1 = *(const short8*)(A + (size_t)ra1 * K + kk + quad * 8);
#pragma unroll
        for (int n = 0; n < 3; n++) {
            int col = n * 16 + l15;
            short8 b = (short8)(short)0;
            if (col < 40) b = *(const short8*)(BT + (size_t)col * K + kk + quad * 8);
            acc[0][n] = __builtin_amdgcn_mfma_f32_16x16x32_bf16(a0, b, acc[0][n], 0, 0, 0);
            acc[1][n] = __builtin_amdgcn_mfma_f32_16x16x32_bf16(a1, b, acc[1][n], 0, 0, 0);
        }
    }
#pragma unroll
    for (int m = 0; m < 2; m++)
#pragma unroll
        for (int n = 0; n < 3; n++)
#pragma unroll
            for (int r = 0; r < 4; r++) {
                int row = row0 + m * 16 + quad * 4 + r;
                int col = n * 16 + l15;
                if (row < M && col < 40)
                    Out[(size_t)row * 40 + col] = acc[m][n][r] + bias[col];
            }
}

// --------------------------- small utility kernels -------------------------
struct TJobs { const float* src[8]; short* dst[8]; int R[8]; int C[8]; };

__global__ void wtrans(TJobs j)  // dst[C][R] = bf16(src[R][C])
{
    int job = blockIdx.y;
    int R = j.R[job], Cc = j.C[job];
    const float* s = j.src[job];
    short* d = j.dst[job];
    int n = R * Cc;
    for (int idx = blockIdx.x * 256 + threadIdx.x; idx < n; idx += gridDim.x * 256) {
        int r = idx / Cc, c = idx - r * Cc;
        d[(size_t)c * R + r] = f2bf(s[idx]);
    }
}

__global__ void zerof(float* p, int n)
{
    int i = blockIdx.x * 256 + threadIdx.x;
    if (i < n) p[i] = 0.f;
}

// ---------------------------------------------------------------------------
extern "C" void kernel_launch(void* const* d_in, const int* in_sizes, int n_in,
                              void* d_out, int out_size, void* d_ws, size_t ws_size,
                              hipStream_t stream)
{
    const float* x    = (const float*)d_in[0];
    // d_in[1] = edge_index: unused (use_graph=False)
    const float* W_in = (const float*)d_in[2];
    const float* b_in = (const float*)d_in[3];
    const float* ln0g = (const float*)d_in[4];
    const float* ln0b = (const float*)d_in[5];
    const float* Wq0  = (const float*)d_in[6];  const float* bq0 = (const float*)d_in[7];
    const float* Wk0  = (const float*)d_in[8];  const float* bk0 = (const float*)d_in[9];
    const float* Wv0  = (const float*)d_in[10]; const float* bv0 = (const float*)d_in[11];
    const float* ln1g = (const float*)d_in[12]; const float* ln1b = (const float*)d_in[13];
    const float* Wq1  = (const float*)d_in[14]; const float* bq1 = (const float*)d_in[15];
    const float* Wk1  = (const float*)d_in[16]; const float* bk1 = (const float*)d_in[17];
    const float* Wv1  = (const float*)d_in[18]; const float* bv1 = (const float*)d_in[19];
    const float* ln2g = (const float*)d_in[20]; const float* ln2b = (const float*)d_in[21];
    const float* W_out = (const float*)d_in[22]; const float* b_out = (const float*)d_in[23];

    const int M = MROWS;
    const int MPAD = GBLK * 64;           // 100032
    char* ws = (char*)d_ws;
    size_t off = 0;
    auto alloc = [&](size_t bytes) -> char* {
        char* p = ws + off;
        off += (bytes + 255) & ~(size_t)255;
        return p;
    };
    short* h = (short*)alloc((size_t)M * HID * 2);
    short* q = (short*)alloc((size_t)M * HID * 2);
    short* k = (short*)alloc((size_t)MPAD * HID * 2);   // fragment layout
    short* v = (short*)alloc((size_t)MPAD * HID * 2);   // fragment layout
    short* WinT  = (short*)alloc((size_t)512 * 256 * 2);
    short* WqT0  = (short*)alloc((size_t)65536 * 2);
    short* WkT0  = (short*)alloc((size_t)65536 * 2);
    short* WvT0  = (short*)alloc((size_t)65536 * 2);
    short* WqT1  = (short*)alloc((size_t)65536 * 2);
    short* WkT1  = (short*)alloc((size_t)65536 * 2);
    short* WvT1  = (short*)alloc((size_t)65536 * 2);
    short* WoutT = (short*)alloc((size_t)40 * 256 * 2);
    float* zbase = (float*)alloc((size_t)(65536 * 2 + 256 * 2 + 4) * 4);
    float* KV0 = zbase;
    float* KV1 = zbase + 65536;
    float* ksum0 = zbase + 131072;
    float* ksum1 = ksum0 + 256;
    float* sq = ksum1 + 256;  // [sq_q0, sq_k0, sq_q1, sq_k1]
    short* KVt0 = (short*)alloc((size_t)272 * 256 * 2);
    short* KVt1 = (short*)alloc((size_t)272 * 256 * 2);

    const int ZN = 65536 * 2 + 256 * 2 + 4;
    zerof<<<dim3((ZN + 255) / 256), 256, 0, stream>>>(zbase, ZN);

    TJobs tj;
    tj.src[0] = W_in;  tj.dst[0] = WinT;  tj.R[0] = 512; tj.C[0] = 256;
    tj.src[1] = Wq0;   tj.dst[1] = WqT0;  tj.R[1] = 256; tj.C[1] = 256;
    tj.src[2] = Wk0;   tj.dst[2] = WkT0;  tj.R[2] = 256; tj.C[2] = 256;
    tj.src[3] = Wv0;   tj.dst[3] = WvT0;  tj.R[3] = 256; tj.C[3] = 256;
    tj.src[4] = Wq1;   tj.dst[4] = WqT1;  tj.R[4] = 256; tj.C[4] = 256;
    tj.src[5] = Wk1;   tj.dst[5] = WkT1;  tj.R[5] = 256; tj.C[5] = 256;
    tj.src[6] = Wv1;   tj.dst[6] = WvT1;  tj.R[6] = 256; tj.C[6] = 256;
    tj.src[7] = W_out; tj.dst[7] = WoutT; tj.R[7] = 256; tj.C[7] = 40;
    wtrans<<<dim3(512, 8), 256, 0, stream>>>(tj);

    const int GB = GBLK;
    const float Nf = (float)M;
    const int ZB = (GBLK + 6) / 7;        // 224

    in_kernel<<<GB, 256, 0, stream>>>(x, WinT, b_in, ln0g, ln0b, h);
    // ---- layer 0 ----
    qkv_kernel<<<GB, 256, 0, stream>>>(h, WqT0, WkT0, WvT0, bq0, bk0, bv0,
                                       q, k, v, sq + 0, sq + 1, ksum0);
    kv_kernel<<<dim3(2, 2, ZB), 256, 0, stream>>>(k, v, KV0, M);
    scale_kernel<<<272, 256, 0, stream>>>(KV0, ksum0, sq + 0, KVt0);
    attn_kernel<<<GB, 256, 0, stream>>>(q, KVt0, v, h, ln1g, ln1b, Nf);
    // ---- layer 1 ----
    qkv_kernel<<<GB, 256, 0, stream>>>(h, WqT1, WkT1, WvT1, bq1, bk1, bv1,
                                       q, k, v, sq + 2, sq + 3, ksum1);
    kv_kernel<<<dim3(2, 2, ZB), 256, 0, stream>>>(k, v, KV1, M);
    scale_kernel<<<272, 256, 0, stream>>>(KV1, ksum1, sq + 2, KVt1);
    attn_kernel<<<GB, 256, 0, stream>>>(q, KVt1, v, h, ln2g, ln2b, Nf);
    // ---- output ----
    gemm_out<<<(M + 127) / 128, 256, 0, stream>>>(h, WoutT, b_out, (float*)d_out, M);
}

// Round 4
// 997.947 us; speedup vs baseline: 1.2753x; 1.1451x over previous
//
#include <hip/hip_runtime.h>

// ---------------------------------------------------------------------------
// SGFormer forward, MI355X/gfx950.  I/O f32; internal h/q/k/v bf16.
// attn = (q @ (k^T v) * s + N*v) / (q . (sum_k) * s + N),  s = 1/(||q|| ||k||)
// KVt[272][256]: rows 0..255 = (KV*s)^T, row 256 = ksum*s, 257..271 = 0.
//
// R7 lesson: qkv with frag stores + per-wave global atomics + no inter-GEMM
// barriers ran 223us vs 145us for the R0 epilogue structure at IDENTICAL
// traffic/occupancy/VGPR.  R8 (this round): restore R0's epilogue skeleton
// (q first + Cb bounce + LDS-scr single-atomic reduction; barrier phases
// between GEMMs) while keeping k/v in fragment layout -- now 16B-packed
// (n-pairs) so each store instruction covers 1KB/wave.  attn reads paired
// v-frags (8x16B); kv decodes the pairing.  A/B: if qkv stays slow, the
// frag stores themselves are the poison -> hard revert next round.
// ---------------------------------------------------------------------------

typedef __attribute__((ext_vector_type(8))) short short8;
typedef __attribute__((ext_vector_type(4))) short short4v;
typedef __attribute__((ext_vector_type(4))) float floatx4;

__device__ __forceinline__ float bf2f(short u) {
    union { unsigned int i; float f; } v;
    v.i = ((unsigned int)(unsigned short)u) << 16;
    return v.f;
}
__device__ __forceinline__ short f2bf(float f) {
    union { float f; unsigned int i; } v; v.f = f;
    unsigned int b = v.i + 0x7fffu + ((v.i >> 16) & 1u);  // RNE
    return (short)(b >> 16);
}

#define HID 256
#define MROWS 100000
#define GBLK 1563            // ceil(MROWS/64)
#define EPSLN 1e-5f

// Paired C-fragment layout: unit = 8 shorts (16B) for (blk, wave, m, p, lane):
// shorts [0..3] = col n=2p   rows {m*16+quad*4+0..3}
// shorts [4..7] = col n=2p+1 rows {m*16+quad*4+0..3}   (col = nb+n*16+l15)
__device__ __forceinline__ size_t frag16off(int blk, int w, int m, int p, int lane) {
    return (((((size_t)blk * 4 + w) * 4 + m) * 2 + p) * 64 + lane);
}

// ---- stage a 64x256 bf16 A-tile into LDS via global_load_lds, XOR-swizzled.
__device__ __forceinline__ void stage_a256(const short* __restrict__ A, short* As,
                                           int row0, int wave, int lane)
{
    const int base = wave * 512;
#pragma unroll
    for (int it = 0; it < 8; ++it) {
        int J = base + it * 64 + lane;
        int row = J >> 5, jj = J & 31;
        int c = jj ^ (row & 31);
        int rowg = min(row0 + row, MROWS - 1);
        const short* gp = A + (size_t)rowg * HID + c * 8;
        __builtin_amdgcn_global_load_lds(
            (const __attribute__((address_space(1))) void*)gp,
            (__attribute__((address_space(3))) void*)&As[(size_t)(base + it * 64) * 8],
            16, 0, 0);
    }
}
// ---- same, linear (no swizzle): for tiles read scalar later.
__device__ __forceinline__ void stage_lin256(const short* __restrict__ A, short* As,
                                             int row0, int wave, int lane)
{
    const int base = wave * 512;
#pragma unroll
    for (int it = 0; it < 8; ++it) {
        int J = base + it * 64 + lane;
        int row = J >> 5, jj = J & 31;
        int rowg = min(row0 + row, MROWS - 1);
        const short* gp = A + (size_t)rowg * HID + jj * 8;
        __builtin_amdgcn_global_load_lds(
            (const __attribute__((address_space(1))) void*)gp,
            (__attribute__((address_space(3))) void*)&As[(size_t)(base + it * 64) * 8],
            16, 0, 0);
    }
}
__device__ __forceinline__ short8 read_a256(const short* As, int m, int ki, int quad, int l15)
{
    int row = m * 16 + l15;
    int phys = (ki * 4 + quad) ^ (row & 31);
    return *(const short8*)&As[((size_t)row * 32 + phys) * 8];
}

// ---------------------------------------------------------------------------
// Fused q/k/v projection.  Order q (bounce) -> k (reductions + frag16) ->
// v (frag16).  R0 epilogue skeleton: LDS-scr staged sumsq (one global atomic
// per block), barrier phases between GEMMs.
// ---------------------------------------------------------------------------
__global__ __launch_bounds__(256, 3)
void qkv_kernel(const short* __restrict__ h,
                const short* __restrict__ BTq, const short* __restrict__ BTk,
                const short* __restrict__ BTv,
                const float* __restrict__ bq, const float* __restrict__ bk,
                const float* __restrict__ bv,
                short* __restrict__ qO, short* __restrict__ kF, short* __restrict__ vF,
                float* __restrict__ sqq, float* __restrict__ sqk,
                float* __restrict__ ksum)
{
    __shared__ short As[64 * 256];      // 32 KB
    __shared__ short Cb[16 * 264];      // 8.25 KB (pad +8: stride 132 dw)
    __shared__ float scr;

    const int tid = threadIdx.x, wave = tid >> 6, lane = tid & 63;
    const int quad = lane >> 4, l15 = lane & 15;
    const int blk = blockIdx.x;
    const int row0 = blk * 64, nb = wave * 64;

    stage_a256(h, As, row0, wave, lane);
    __syncthreads();

    floatx4 acc[4][4];

    auto gemm256 = [&](const short* __restrict__ BT) {
#pragma unroll
        for (int m = 0; m < 4; m++)
#pragma unroll
            for (int n = 0; n < 4; n++) acc[m][n] = (floatx4)0.0f;
#pragma unroll
        for (int ki = 0; ki < 8; ++ki) {
            short8 a[4];
#pragma unroll
            for (int m = 0; m < 4; ++m) a[m] = read_a256(As, m, ki, quad, l15);
#pragma unroll
            for (int n = 0; n < 4; ++n) {
                short8 b = *(const short8*)(BT + (size_t)(nb + n * 16 + l15) * 256 + ki * 32 + quad * 8);
#pragma unroll
                for (int m = 0; m < 4; ++m)
                    acc[m][n] = __builtin_amdgcn_mfma_f32_16x16x32_bf16(a[m], b, acc[m][n], 0, 0, 0);
            }
        }
    };

    float bn[4];

    // ---------------- Q ----------------
    gemm256(BTq);
#pragma unroll
    for (int n = 0; n < 4; n++) bn[n] = bq[nb + n * 16 + l15];
    {
        float ssq = 0.f;
#pragma unroll
        for (int m = 0; m < 4; m++)
#pragma unroll
            for (int r = 0; r < 4; r++) {
                int rl = m * 16 + quad * 4 + r;
                bool valid = (row0 + rl) < MROWS;
#pragma unroll
                for (int n = 0; n < 4; n++) {
                    float val = acc[m][n][r] + bn[n];
                    acc[m][n][r] = val;
                    if (valid) ssq += val * val;
                }
            }
#pragma unroll
        for (int off = 32; off; off >>= 1) ssq += __shfl_down(ssq, off);
        if (tid == 0) scr = 0.f;
        __syncthreads();
        if (lane == 0) atomicAdd(&scr, ssq);
        __syncthreads();
        if (tid == 0) atomicAdd(sqq, scr);
    }
    // bounce q row-major (coalesced 512B lines)
#pragma unroll
    for (int m = 0; m < 4; ++m) {
        __syncthreads();
#pragma unroll
        for (int n = 0; n < 4; ++n)
#pragma unroll
            for (int r = 0; r < 4; ++r)
                Cb[(quad * 4 + r) * 264 + nb + n * 16 + l15] = f2bf(acc[m][n][r]);
        __syncthreads();
#pragma unroll
        for (int ch = tid; ch < 512; ch += 256) {
            int rl = ch >> 5, co = (ch & 31) * 8;
            int row = row0 + m * 16 + rl;
            if (row < MROWS)
                *(short8*)(qO + (size_t)row * 256 + co) = *(const short8*)&Cb[rl * 264 + co];
        }
    }

    // ---------------- K ----------------
    gemm256(BTk);
#pragma unroll
    for (int n = 0; n < 4; n++) bn[n] = bk[nb + n * 16 + l15];
    {
        float ssq = 0.f;
        float csum[4] = {0.f, 0.f, 0.f, 0.f};
#pragma unroll
        for (int m = 0; m < 4; m++)
#pragma unroll
            for (int r = 0; r < 4; r++) {
                int rl = m * 16 + quad * 4 + r;
                bool valid = (row0 + rl) < MROWS;
#pragma unroll
                for (int n = 0; n < 4; n++) {
                    float val = acc[m][n][r] + bn[n];
                    acc[m][n][r] = val;
                    if (valid) { ssq += val * val; csum[n] += val; }
                }
            }
#pragma unroll
        for (int off = 32; off; off >>= 1) ssq += __shfl_down(ssq, off);
        if (tid == 0) scr = 0.f;
        __syncthreads();
        if (lane == 0) atomicAdd(&scr, ssq);
        __syncthreads();
        if (tid == 0) atomicAdd(sqk, scr);
#pragma unroll
        for (int n = 0; n < 4; n++) {
            float cv = csum[n];
            cv += __shfl_xor(cv, 16);
            cv += __shfl_xor(cv, 32);
            if (quad == 0) atomicAdd(&ksum[nb + n * 16 + l15], cv);
        }
        // paired frag stores: 16B/lane, 1KB/wave per instruction
#pragma unroll
        for (int m = 0; m < 4; ++m)
#pragma unroll
            for (int p = 0; p < 2; ++p) {
                short8 s8;
#pragma unroll
                for (int r = 0; r < 4; ++r) {
                    s8[r]     = f2bf(acc[m][2 * p][r]);
                    s8[4 + r] = f2bf(acc[m][2 * p + 1][r]);
                }
                *(short8*)(kF + frag16off(blk, wave, m, p, lane) * 8) = s8;
            }
    }

    // ---------------- V ----------------
    gemm256(BTv);
#pragma unroll
    for (int n = 0; n < 4; n++) bn[n] = bv[nb + n * 16 + l15];
#pragma unroll
    for (int m = 0; m < 4; ++m)
#pragma unroll
        for (int p = 0; p < 2; ++p) {
            short8 s8;
#pragma unroll
            for (int r = 0; r < 4; ++r) {
                s8[r]     = f2bf(acc[m][2 * p][r] + bn[2 * p]);
                s8[4 + r] = f2bf(acc[m][2 * p + 1][r] + bn[2 * p + 1]);
            }
            *(short8*)(vF + frag16off(blk, wave, m, p, lane) * 8) = s8;
        }
}

// ---------------------------------------------------------------------------
// Attention epilogue GEMM: acc = q @ KVt_s (den col = KVt row 256, wave 0);
// h = 0.5*(acc + N*v)/den + 0.5*h; LayerNorm; in-place.
// v read in paired fragment layout (8x 16B loads).  h staged into As (dead
// after MFMA) while fold-1 computes.  Cb/rowm/rowr aliased into As.
// ---------------------------------------------------------------------------
__global__ __launch_bounds__(256, 3)
void attn_kernel(const short* __restrict__ q, const short* __restrict__ KVt,
                 const short* __restrict__ vF, short* __restrict__ h,
                 const float* __restrict__ lng, const float* __restrict__ lnb,
                 float Nf)
{
    __shared__ short As[64 * 256];      // 32 KB
    __shared__ float denA[64];
    __shared__ float redS[64][4], redQ[64][4];
    short* Cb = As;                     // alias: bytes [0, 8448) stride 264
    float* rowm = (float*)&As[4352];    // bytes [8704, 8960)
    float* rowr = (float*)&As[4480];    // bytes [8960, 9216)

    const int tid = threadIdx.x, wave = tid >> 6, lane = tid & 63;
    const int quad = lane >> 4, l15 = lane & 15;
    const int blk = blockIdx.x;
    const int row0 = blk * 64, nb = wave * 64;

    stage_a256(q, As, row0, wave, lane);
    __syncthreads();

    floatx4 acc[4][4];
#pragma unroll
    for (int m = 0; m < 4; m++)
#pragma unroll
        for (int n = 0; n < 4; n++) acc[m][n] = (floatx4)0.0f;
    floatx4 accd[4];
#pragma unroll
    for (int m = 0; m < 4; m++) accd[m] = (floatx4)0.0f;

#pragma unroll
    for (int ki = 0; ki < 8; ++ki) {
        short8 a[4];
#pragma unroll
        for (int m = 0; m < 4; ++m) a[m] = read_a256(As, m, ki, quad, l15);
#pragma unroll
        for (int n = 0; n < 4; ++n) {
            short8 b = *(const short8*)(KVt + (size_t)(nb + n * 16 + l15) * 256 + ki * 32 + quad * 8);
#pragma unroll
            for (int m = 0; m < 4; ++m)
                acc[m][n] = __builtin_amdgcn_mfma_f32_16x16x32_bf16(a[m], b, acc[m][n], 0, 0, 0);
        }
        if (wave == 0) {
            short8 bd = *(const short8*)(KVt + (size_t)(256 + l15) * 256 + ki * 32 + quad * 8);
#pragma unroll
            for (int m = 0; m < 4; ++m)
                accd[m] = __builtin_amdgcn_mfma_f32_16x16x32_bf16(a[m], bd, accd[m], 0, 0, 0);
        }
    }
    // paired v fragment loads (latency hidden under denA + fold-1 setup)
    short8 vp[4][2];
#pragma unroll
    for (int m = 0; m < 4; ++m)
#pragma unroll
        for (int p = 0; p < 2; ++p)
            vp[m][p] = *(const short8*)(vF + frag16off(blk, wave, m, p, lane) * 8);

    if (wave == 0 && l15 == 0) {
#pragma unroll
        for (int m = 0; m < 4; m++)
#pragma unroll
            for (int r = 0; r < 4; r++)
                denA[m * 16 + quad * 4 + r] = accd[m][r];
    }
    __syncthreads();   // As reads done everywhere; denA visible

    // issue h staging now; completes at the next barrier (hidden under fold-1)
    stage_lin256(h, As, row0, wave, lane);

    // fold-1: acc = 0.5*(acc + N*v)/den   (no As use)
#pragma unroll
    for (int m = 0; m < 4; m++)
#pragma unroll
        for (int r = 0; r < 4; r++) {
            int rl = m * 16 + quad * 4 + r;
            float rden = 1.0f / (denA[rl] + Nf);
#pragma unroll
            for (int n = 0; n < 4; n++) {
                float vv = bf2f(vp[m][n >> 1][(n & 1) * 4 + r]);
                acc[m][n][r] = 0.5f * (acc[m][n][r] + Nf * vv) * rden;
            }
        }
    __syncthreads();   // h staged (barrier drains vmcnt)

    // fold-2: acc += 0.5*h ; LN stats
#pragma unroll
    for (int m = 0; m < 4; m++)
#pragma unroll
        for (int r = 0; r < 4; r++) {
            int rl = m * 16 + quad * 4 + r;
            float s = 0.f, s2 = 0.f;
#pragma unroll
            for (int n = 0; n < 4; n++) {
                int col = nb + n * 16 + l15;
                float pv = bf2f(As[(size_t)rl * 256 + col]);
                float val = acc[m][n][r] + 0.5f * pv;
                acc[m][n][r] = val;
                s += val; s2 += val * val;
            }
#pragma unroll
            for (int off = 1; off < 16; off <<= 1) {
                s += __shfl_xor(s, off);
                s2 += __shfl_xor(s2, off);
            }
            if (l15 == 0) { redS[rl][wave] = s; redQ[rl][wave] = s2; }
        }
    __syncthreads();   // all As (h) reads done; alias region now writable
    if (tid < 64) {
        float s = redS[tid][0] + redS[tid][1] + redS[tid][2] + redS[tid][3];
        float s2 = redQ[tid][0] + redQ[tid][1] + redQ[tid][2] + redQ[tid][3];
        float mean = s * (1.0f / 256.0f);
        float var = s2 * (1.0f / 256.0f) - mean * mean;
        rowm[tid] = mean;
        rowr[tid] = rsqrtf(var + EPSLN);
    }
    float g[4], bb[4];
#pragma unroll
    for (int n = 0; n < 4; n++) {
        g[n] = lng[nb + n * 16 + l15];
        bb[n] = lnb[nb + n * 16 + l15];
    }
#pragma unroll
    for (int m = 0; m < 4; ++m) {
        __syncthreads();   // m=0: rowm/rowr visible; m>0: prior drain done
#pragma unroll
        for (int n = 0; n < 4; ++n)
#pragma unroll
            for (int r = 0; r < 4; ++r) {
                int rl = m * 16 + quad * 4 + r;
                float x = (acc[m][n][r] - rowm[rl]) * rowr[rl] * g[n] + bb[n];
                Cb[(quad * 4 + r) * 264 + nb + n * 16 + l15] = f2bf(x);
            }
        __syncthreads();
#pragma unroll
        for (int ch = tid; ch < 512; ch += 256) {
            int rl = ch >> 5, co = (ch & 31) * 8;
            int row = row0 + m * 16 + rl;
            if (row < MROWS)
                *(short8*)(h + (size_t)row * 256 + co) = *(const short8*)&Cb[rl * 264 + co];
        }
    }
}

// ---------------------------------------------------------------------------
// Stage 0: h = relu(LN(x @ W_in + b_in)); x f32, K=512, slabbed KTILE=128.
// Double-buffered LDS slabs + reg-staged x prefetch.
// ---------------------------------------------------------------------------
__global__ __launch_bounds__(256, 3)
void in_kernel(const float* __restrict__ x, const short* __restrict__ WinT,
               const float* __restrict__ b_in, const float* __restrict__ lng,
               const float* __restrict__ lnb, short* __restrict__ h)
{
    __shared__ short As[2][64 * 128];   // 2 x 16 KB
    __shared__ short Cb[16 * 264];
    __shared__ float redS[64][4], redQ[64][4];
    __shared__ float rowm[64], rowr[64];

    const int tid = threadIdx.x, wave = tid >> 6, lane = tid & 63;
    const int quad = lane >> 4, l15 = lane & 15;
    const int row0 = blockIdx.x * 64, nb = wave * 64;

    floatx4 acc[4][4];
#pragma unroll
    for (int m = 0; m < 4; m++)
#pragma unroll
        for (int n = 0; n < 4; n++) acc[m][n] = (floatx4)0.0f;

    floatx4 xr[4][2];
    auto issue = [&](int slab) {
#pragma unroll
        for (int it = 0; it < 4; ++it) {
            int J = it * 256 + tid;
            int row = J >> 4, jj = J & 15, c = jj ^ (row & 15);
            int rowg = min(row0 + row, MROWS - 1);
            const float* gp = x + (size_t)rowg * 512 + slab + c * 8;
            xr[it][0] = *(const floatx4*)gp;
            xr[it][1] = *(const floatx4*)(gp + 4);
        }
    };
    auto commit = [&](short* dst) {
#pragma unroll
        for (int it = 0; it < 4; ++it) {
            int J = it * 256 + tid;
            short8 s8;
#pragma unroll
            for (int i = 0; i < 4; ++i) { s8[i] = f2bf(xr[it][0][i]); s8[i + 4] = f2bf(xr[it][1][i]); }
            *(short8*)&dst[(size_t)J * 8] = s8;
        }
    };

    issue(0);
    commit(As[0]);
    __syncthreads();

#pragma unroll
    for (int s = 0; s < 4; ++s) {
        if (s < 3) issue((s + 1) * 128);          // x loads in flight under MFMAs
        const short* cur = As[s & 1];
#pragma unroll
        for (int ki = 0; ki < 4; ++ki) {
            short8 a[4];
#pragma unroll
            for (int m = 0; m < 4; ++m) {
                int row = m * 16 + l15;
                int phys = (ki * 4 + quad) ^ (row & 15);
                a[m] = *(const short8*)&cur[((size_t)row * 16 + phys) * 8];
            }
#pragma unroll
            for (int n = 0; n < 4; ++n) {
                short8 b = *(const short8*)(WinT + (size_t)(nb + n * 16 + l15) * 512 + s * 128 + ki * 32 + quad * 8);
#pragma unroll
                for (int m = 0; m < 4; ++m)
                    acc[m][n] = __builtin_amdgcn_mfma_f32_16x16x32_bf16(a[m], b, acc[m][n], 0, 0, 0);
            }
        }
        if (s < 3) {
            commit(As[(s + 1) & 1]);
            __syncthreads();
        }
    }
    // bias + LN stats
    float bn[4];
#pragma unroll
    for (int n = 0; n < 4; n++) bn[n] = b_in[nb + n * 16 + l15];
#pragma unroll
    for (int m = 0; m < 4; m++)
#pragma unroll
        for (int r = 0; r < 4; r++) {
            int rl = m * 16 + quad * 4 + r;
            float s = 0.f, s2 = 0.f;
#pragma unroll
            for (int n = 0; n < 4; n++) {
                float val = acc[m][n][r] + bn[n];
                acc[m][n][r] = val;
                s += val; s2 += val * val;
            }
#pragma unroll
            for (int off = 1; off < 16; off <<= 1) {
                s += __shfl_xor(s, off);
                s2 += __shfl_xor(s2, off);
            }
            if (l15 == 0) { redS[rl][wave] = s; redQ[rl][wave] = s2; }
        }
    __syncthreads();
    if (tid < 64) {
        float s = redS[tid][0] + redS[tid][1] + redS[tid][2] + redS[tid][3];
        float s2 = redQ[tid][0] + redQ[tid][1] + redQ[tid][2] + redQ[tid][3];
        float mean = s * (1.0f / 256.0f);
        float var = s2 * (1.0f / 256.0f) - mean * mean;
        rowm[tid] = mean;
        rowr[tid] = rsqrtf(var + EPSLN);
    }
    __syncthreads();
    float g[4], bb[4];
#pragma unroll
    for (int n = 0; n < 4; n++) {
        g[n] = lng[nb + n * 16 + l15];
        bb[n] = lnb[nb + n * 16 + l15];
    }
#pragma unroll
    for (int m = 0; m < 4; ++m) {
        __syncthreads();
#pragma unroll
        for (int n = 0; n < 4; ++n)
#pragma unroll
            for (int r = 0; r < 4; ++r) {
                int rl = m * 16 + quad * 4 + r;
                float xv = (acc[m][n][r] - rowm[rl]) * rowr[rl] * g[n] + bb[n];
                Cb[(quad * 4 + r) * 264 + nb + n * 16 + l15] = f2bf(fmaxf(xv, 0.f));
            }
        __syncthreads();
#pragma unroll
        for (int ch = tid; ch < 512; ch += 256) {
            int rl = ch >> 5, co = (ch & 31) * 8;
            int row = row0 + m * 16 + rl;
            if (row < MROWS)
                *(short8*)(h + (size_t)row * 256 + co) = *(const short8*)&Cb[rl * 264 + co];
        }
    }
}

// ---------------------------------------------------------------------------
// KV = k^T @ v  [256x256] f32, split over grid.z (224 x 7 blk64), frag input.
// Each 32-row stripe: frag16-decode -> 8B ds_writes into transposed LDS
// tiles; next stripe register-prefetched under the MFMAs.
// ---------------------------------------------------------------------------
__global__ __launch_bounds__(256)
void kv_kernel(const short* __restrict__ kF, const short* __restrict__ vF,
               float* __restrict__ KV, int M)
{
    __shared__ short ksT[128][40];
    __shared__ short vsT[128][40];
    const int t = threadIdx.x, wave = t >> 6, lane = t & 63;
    const int quad = lane >> 4, l15 = lane & 15;
    const int mb = blockIdx.x * 128, nbb = blockIdx.y * 128;
    const int bbeg = blockIdx.z * 7;
    const int bend = min(GBLK, bbeg + 7);

    floatx4 acc[2][8];
#pragma unroll
    for (int m = 0; m < 2; m++)
#pragma unroll
        for (int j = 0; j < 8; j++) acc[m][j] = (floatx4)0.0f;

    const int wm = wave * 32;

    short4v kc[4], vc[4];
    auto loadstripe = [&](int blk, int half) {
#pragma unroll
        for (int i = 0; i < 4; ++i) {
            int ci = t + i * 256;
            int colc = ci & 127, rowg = ci >> 7;       // rowg in 0..7
            int qs = rowg & 3, mi = rowg >> 2;
            int m = half * 2 + mi;
            bool valid = (blk * 64 + m * 16 + qs * 4) < M;
            int Ck = mb + colc, Cv = nbb + colc;
            size_t ok = frag16off(blk, Ck >> 6, m, (Ck >> 5) & 1, qs * 16 + (Ck & 15)) * 8
                        + (size_t)((Ck >> 4) & 1) * 4;
            size_t ov = frag16off(blk, Cv >> 6, m, (Cv >> 5) & 1, qs * 16 + (Cv & 15)) * 8
                        + (size_t)((Cv >> 4) & 1) * 4;
            kc[i] = valid ? *(const short4v*)(kF + ok) : (short4v)(short)0;
            vc[i] = valid ? *(const short4v*)(vF + ov) : (short4v)(short)0;
        }
    };
    auto commit = [&]() {
#pragma unroll
        for (int i = 0; i < 4; ++i) {
            int ci = t + i * 256;
            int colc = ci & 127, rowg = ci >> 7;
            *(short4v*)&ksT[colc][rowg * 4] = kc[i];   // lr = mi*16+qs*4 = rowg*4
            *(short4v*)&vsT[colc][rowg * 4] = vc[i];
        }
    };

    loadstripe(bbeg, 0);
    for (int blk = bbeg; blk < bend; ++blk)
#pragma unroll
        for (int half = 0; half < 2; ++half) {
            __syncthreads();
            commit();
            __syncthreads();
            bool more = !(blk == bend - 1 && half == 1);
            short8 a0 = *(const short8*)&ksT[wm + l15][quad * 8];
            short8 a1 = *(const short8*)&ksT[wm + 16 + l15][quad * 8];
            if (more) loadstripe(half ? blk + 1 : blk, half ^ 1);   // prefetch
#pragma unroll
            for (int j = 0; j < 8; j++) {
                short8 b = *(const short8*)&vsT[j * 16 + l15][quad * 8];
                acc[0][j] = __builtin_amdgcn_mfma_f32_16x16x32_bf16(a0, b, acc[0][j], 0, 0, 0);
                acc[1][j] = __builtin_amdgcn_mfma_f32_16x16x32_bf16(a1, b, acc[1][j], 0, 0, 0);
            }
        }
#pragma unroll
    for (int mi = 0; mi < 2; mi++)
#pragma unroll
        for (int j = 0; j < 8; j++)
#pragma unroll
            for (int r = 0; r < 4; r++) {
                int m = mb + wm + mi * 16 + quad * 4 + r;
                int n = nbb + j * 16 + l15;
                atomicAdd(&KV[(size_t)m * HID + n], acc[mi][j][r]);
            }
}

// KVt[272][256]: rows 0..255 = (KV*s)^T bf16, row 256 = ksum*s, 257..271 = 0
__global__ void scale_kernel(const float* __restrict__ KV, const float* __restrict__ ksum,
                             const float* __restrict__ sq, short* __restrict__ KVt)
{
    float s = rsqrtf(sq[0]) * rsqrtf(sq[1]);
    int d = blockIdx.x;   // 0..271
    int m = threadIdx.x;  // 0..255
    float val;
    if (d < 256)       val = KV[(size_t)m * HID + d] * s;
    else if (d == 256) val = ksum[m] * s;
    else               val = 0.f;
    KVt[(size_t)d * HID + m] = f2bf(val);
}

// ---------------------------------------------------------------------------
// Final GEMM: Out[M,40] = h[M,256] @ W_out[256,40] + b_out
// ---------------------------------------------------------------------------
__global__ __launch_bounds__(256)
void gemm_out(const short* __restrict__ A, const short* __restrict__ BT,
              const float* __restrict__ bias, float* __restrict__ Out, int M)
{
    const int tid = threadIdx.x, wave = tid >> 6, lane = tid & 63;
    const int quad = lane >> 4, l15 = lane & 15;
    const int row0 = blockIdx.x * 128 + wave * 32;
    const int K = 256;
    floatx4 acc[2][3];
#pragma unroll
    for (int m = 0; m < 2; m++)
#pragma unroll
        for (int n = 0; n < 3; n++) acc[m][n] = (floatx4)0.0f;

    int ra0 = min(row0 + l15, M - 1);
    int ra1 = min(row0 + 16 + l15, M - 1);
    for (int kk = 0; kk < K; kk += 32) {
        short8 a0 = *(const short8*)(A + (size_t)ra0 * K + kk + quad * 8);
        short8 a1 = *(const short8*)(A + (size_t)ra1 * K + kk + quad * 8);
#pragma unroll
        for (int n = 0; n < 3; n++) {
            int col = n * 16 + l15;
            short8 b = (short8)(short)0;
            if (col < 40) b = *(const short8*)(BT + (size_t)col * K + kk + quad * 8);
            acc[0][n] = __builtin_amdgcn_mfma_f32_16x16x32_bf16(a0, b, acc[0][n], 0, 0, 0);
            acc[1][n] = __builtin_amdgcn_mfma_f32_16x16x32_bf16(a1, b, acc[1][n], 0, 0, 0);
        }
    }
#pragma unroll
    for (int m = 0; m < 2; m++)
#pragma unroll
        for (int n = 0; n < 3; n++)
#pragma unroll
            for (int r = 0; r < 4; r++) {
                int row = row0 + m * 16 + quad * 4 + r;
                int col = n * 16 + l15;
                if (row < M && col < 40)
                    Out[(size_t)row * 40 + col] = acc[m][n][r] + bias[col];
            }
}

// --------------------------- small utility kernels -------------------------
struct TJobs { const float* src[8]; short* dst[8]; int R[8]; int C[8]; };

__global__ void wtrans(TJobs j)  // dst[C][R] = bf16(src[R][C])
{
    int job = blockIdx.y;
    int R = j.R[job], Cc = j.C[job];
    const float* s = j.src[job];
    short* d = j.dst[job];
    int n = R * Cc;
    for (int idx = blockIdx.x * 256 + threadIdx.x; idx < n; idx += gridDim.x * 256) {
        int r = idx / Cc, c = idx - r * Cc;
        d[(size_t)c * R + r] = f2bf(s[idx]);
    }
}

__global__ void zerof(float* p, int n)
{
    int i = blockIdx.x * 256 + threadIdx.x;
    if (i < n) p[i] = 0.f;
}

// ---------------------------------------------------------------------------
extern "C" void kernel_launch(void* const* d_in, const int* in_sizes, int n_in,
                              void* d_out, int out_size, void* d_ws, size_t ws_size,
                              hipStream_t stream)
{
    const float* x    = (const float*)d_in[0];
    // d_in[1] = edge_index: unused (use_graph=False)
    const float* W_in = (const float*)d_in[2];
    const float* b_in = (const float*)d_in[3];
    const float* ln0g = (const float*)d_in[4];
    const float* ln0b = (const float*)d_in[5];
    const float* Wq0  = (const float*)d_in[6];  const float* bq0 = (const float*)d_in[7];
    const float* Wk0  = (const float*)d_in[8];  const float* bk0 = (const float*)d_in[9];
    const float* Wv0  = (const float*)d_in[10]; const float* bv0 = (const float*)d_in[11];
    const float* ln1g = (const float*)d_in[12]; const float* ln1b = (const float*)d_in[13];
    const float* Wq1  = (const float*)d_in[14]; const float* bq1 = (const float*)d_in[15];
    const float* Wk1  = (const float*)d_in[16]; const float* bk1 = (const float*)d_in[17];
    const float* Wv1  = (const float*)d_in[18]; const float* bv1 = (const float*)d_in[19];
    const float* ln2g = (const float*)d_in[20]; const float* ln2b = (const float*)d_in[21];
    const float* W_out = (const float*)d_in[22]; const float* b_out = (const float*)d_in[23];

    const int M = MROWS;
    const int MPAD = GBLK * 64;           // 100032
    char* ws = (char*)d_ws;
    size_t off = 0;
    auto alloc = [&](size_t bytes) -> char* {
        char* p = ws + off;
        off += (bytes + 255) & ~(size_t)255;
        return p;
    };
    short* h = (short*)alloc((size_t)M * HID * 2);
    short* q = (short*)alloc((size_t)M * HID * 2);
    short* k = (short*)alloc((size_t)MPAD * HID * 2);   // paired fragment layout
    short* v = (short*)alloc((size_t)MPAD * HID * 2);   // paired fragment layout
    short* WinT  = (short*)alloc((size_t)512 * 256 * 2);
    short* WqT0  = (short*)alloc((size_t)65536 * 2);
    short* WkT0  = (short*)alloc((size_t)65536 * 2);
    short* WvT0  = (short*)alloc((size_t)65536 * 2);
    short* WqT1  = (short*)alloc((size_t)65536 * 2);
    short* WkT1  = (short*)alloc((size_t)65536 * 2);
    short* WvT1  = (short*)alloc((size_t)65536 * 2);
    short* WoutT = (short*)alloc((size_t)40 * 256 * 2);
    float* zbase = (float*)alloc((size_t)(65536 * 2 + 256 * 2 + 4) * 4);
    float* KV0 = zbase;
    float* KV1 = zbase + 65536;
    float* ksum0 = zbase + 131072;
    float* ksum1 = ksum0 + 256;
    float* sq = ksum1 + 256;  // [sq_q0, sq_k0, sq_q1, sq_k1]
    short* KVt0 = (short*)alloc((size_t)272 * 256 * 2);
    short* KVt1 = (short*)alloc((size_t)272 * 256 * 2);

    const int ZN = 65536 * 2 + 256 * 2 + 4;
    zerof<<<dim3((ZN + 255) / 256), 256, 0, stream>>>(zbase, ZN);

    TJobs tj;
    tj.src[0] = W_in;  tj.dst[0] = WinT;  tj.R[0] = 512; tj.C[0] = 256;
    tj.src[1] = Wq0;   tj.dst[1] = WqT0;  tj.R[1] = 256; tj.C[1] = 256;
    tj.src[2] = Wk0;   tj.dst[2] = WkT0;  tj.R[2] = 256; tj.C[2] = 256;
    tj.src[3] = Wv0;   tj.dst[3] = WvT0;  tj.R[3] = 256; tj.C[3] = 256;
    tj.src[4] = Wq1;   tj.dst[4] = WqT1;  tj.R[4] = 256; tj.C[4] = 256;
    tj.src[5] = Wk1;   tj.dst[5] = WkT1;  tj.R[5] = 256; tj.C[5] = 256;
    tj.src[6] = Wv1;   tj.dst[6] = WvT1;  tj.R[6] = 256; tj.C[6] = 256;
    tj.src[7] = W_out; tj.dst[7] = WoutT; tj.R[7] = 256; tj.C[7] = 40;
    wtrans<<<dim3(512, 8), 256, 0, stream>>>(tj);

    const int GB = GBLK;
    const float Nf = (float)M;
    const int ZB = (GBLK + 6) / 7;        // 224

    in_kernel<<<GB, 256, 0, stream>>>(x, WinT, b_in, ln0g, ln0b, h);
    // ---- layer 0 ----
    qkv_kernel<<<GB, 256, 0, stream>>>(h, WqT0, WkT0, WvT0, bq0, bk0, bv0,
                                       q, k, v, sq + 0, sq + 1, ksum0);
    kv_kernel<<<dim3(2, 2, ZB), 256, 0, stream>>>(k, v, KV0, M);
    scale_kernel<<<272, 256, 0, stream>>>(KV0, ksum0, sq + 0, KVt0);
    attn_kernel<<<GB, 256, 0, stream>>>(q, KVt0, v, h, ln1g, ln1b, Nf);
    // ---- layer 1 ----
    qkv_kernel<<<GB, 256, 0, stream>>>(h, WqT1, WkT1, WvT1, bq1, bk1, bv1,
                                       q, k, v, sq + 2, sq + 3, ksum1);
    kv_kernel<<<dim3(2, 2, ZB), 256, 0, stream>>>(k, v, KV1, M);
    scale_kernel<<<272, 256, 0, stream>>>(KV1, ksum1, sq + 2, KVt1);
    attn_kernel<<<GB, 256, 0, stream>>>(q, KVt1, v, h, ln2g, ln2b, Nf);
    // ---- output ----
    gemm_out<<<(M + 127) / 128, 256, 0, stream>>>(h, WoutT, b_out, (float*)d_out, M);
}